// Round 1
// baseline (2125.572 us; speedup 1.0000x reference)
//
#include <hip/hip_runtime.h>
#include <math.h>

#define TT   2048
#define BB   8
#define DIM_ 1024
#define DI_  2048
#define NS_  64
#define MR_  (TT * BB)   // 16384 rows (t-major, b-minor)

// ---------------------------------------------------------------------------
// Wf[n][d] = sum_i W*[n][i] * W_in[i][d]  for n in [0,256)
// rows 0..63 = W_k, 64..127 = W_v, 128..191 = W_q, 192..255 = W_z
// grid (DIM/256, 64), 256 threads. Each thread does one d for all 4 gates.
// ---------------------------------------------------------------------------
__global__ __launch_bounds__(256) void fuse_w_kernel(
    const float* __restrict__ Wk, const float* __restrict__ Wv,
    const float* __restrict__ Wq, const float* __restrict__ Wz,
    const float* __restrict__ Win, float* __restrict__ Wf) {
  const int d  = blockIdx.x * 256 + threadIdx.x;
  const int n0 = blockIdx.y;  // 0..63
  const float* rk = Wk + (size_t)n0 * DI_;
  const float* rv = Wv + (size_t)n0 * DI_;
  const float* rq = Wq + (size_t)n0 * DI_;
  const float* rz = Wz + (size_t)n0 * DI_;
  float a0 = 0.f, a1 = 0.f, a2 = 0.f, a3 = 0.f;
#pragma unroll 4
  for (int i = 0; i < DI_; ++i) {
    float w = Win[(size_t)i * DIM_ + d];  // coalesced across lanes
    a0 = fmaf(rk[i], w, a0);              // wave-uniform scalars
    a1 = fmaf(rv[i], w, a1);
    a2 = fmaf(rq[i], w, a2);
    a3 = fmaf(rz[i], w, a3);
  }
  Wf[(size_t)(n0      ) * DIM_ + d] = a0;
  Wf[(size_t)(n0 +  64) * DIM_ + d] = a1;
  Wf[(size_t)(n0 + 128) * DIM_ + d] = a2;
  Wf[(size_t)(n0 + 192) * DIM_ + d] = a3;
}

// ---------------------------------------------------------------------------
// Generic fp32 tiled GEMM:  C[M,N] = A[M,K] * B[N,K]^T   (both K-major)
// 128x128 block tile, BK=16, 256 threads, 8x8 micro-tile per thread.
// All M,N,K here are multiples of the tile dims -> no bounds checks.
// ---------------------------------------------------------------------------
__global__ __launch_bounds__(256) void gemm_abt(
    const float* __restrict__ A, const float* __restrict__ B,
    float* __restrict__ C, int M, int N, int K) {
  // pad to 132 floats: keeps float4 rows 16B-aligned, ~2-way bank alias (free)
  __shared__ __align__(16) float As[16][132];
  __shared__ __align__(16) float Bs[16][132];
  const int tid  = threadIdx.x;
  const int m0   = blockIdx.y * 128;
  const int n0   = blockIdx.x * 128;
  const int lrow = tid >> 2;        // 0..63
  const int lk4  = (tid & 3) << 2;  // 0,4,8,12
  const int tm   = (tid & 15) << 2; // 0..60
  const int tn   = (tid >> 4) << 2; // 0..60
  float acc[8][8];
#pragma unroll
  for (int i = 0; i < 8; ++i)
#pragma unroll
    for (int j = 0; j < 8; ++j) acc[i][j] = 0.f;

  for (int k0 = 0; k0 < K; k0 += 16) {
    float4 av0 = *(const float4*)&A[(size_t)(m0 + lrow)      * K + k0 + lk4];
    float4 av1 = *(const float4*)&A[(size_t)(m0 + 64 + lrow) * K + k0 + lk4];
    float4 bv0 = *(const float4*)&B[(size_t)(n0 + lrow)      * K + k0 + lk4];
    float4 bv1 = *(const float4*)&B[(size_t)(n0 + 64 + lrow) * K + k0 + lk4];
    __syncthreads();  // previous tile fully consumed before overwrite
    As[lk4 + 0][lrow] = av0.x; As[lk4 + 1][lrow] = av0.y;
    As[lk4 + 2][lrow] = av0.z; As[lk4 + 3][lrow] = av0.w;
    As[lk4 + 0][64 + lrow] = av1.x; As[lk4 + 1][64 + lrow] = av1.y;
    As[lk4 + 2][64 + lrow] = av1.z; As[lk4 + 3][64 + lrow] = av1.w;
    Bs[lk4 + 0][lrow] = bv0.x; Bs[lk4 + 1][lrow] = bv0.y;
    Bs[lk4 + 2][lrow] = bv0.z; Bs[lk4 + 3][lrow] = bv0.w;
    Bs[lk4 + 0][64 + lrow] = bv1.x; Bs[lk4 + 1][64 + lrow] = bv1.y;
    Bs[lk4 + 2][64 + lrow] = bv1.z; Bs[lk4 + 3][64 + lrow] = bv1.w;
    __syncthreads();
#pragma unroll
    for (int kk = 0; kk < 16; ++kk) {
      float4 a0 = *(const float4*)&As[kk][tm];
      float4 a1 = *(const float4*)&As[kk][tm + 64];
      float4 b0 = *(const float4*)&Bs[kk][tn];
      float4 b1 = *(const float4*)&Bs[kk][tn + 64];
      float ar[8] = {a0.x, a0.y, a0.z, a0.w, a1.x, a1.y, a1.z, a1.w};
      float br[8] = {b0.x, b0.y, b0.z, b0.w, b1.x, b1.y, b1.z, b1.w};
#pragma unroll
      for (int i = 0; i < 8; ++i)
#pragma unroll
        for (int j = 0; j < 8; ++j)
          acc[i][j] = fmaf(ar[i], br[j], acc[i][j]);
    }
  }
#pragma unroll
  for (int i = 0; i < 8; ++i) {
    int r = m0 + tm + (i & 3) + ((i >> 2) << 6);
    float4 c0 = make_float4(acc[i][0], acc[i][1], acc[i][2], acc[i][3]);
    float4 c1 = make_float4(acc[i][4], acc[i][5], acc[i][6], acc[i][7]);
    *(float4*)&C[(size_t)r * N + n0 + tn]      = c0;
    *(float4*)&C[(size_t)r * N + n0 + tn + 64] = c1;
  }
}

// ---------------------------------------------------------------------------
// Unit-normalize each k row (first 64 cols of kvqz): one wave per row.
// grid MR/4 blocks x 256 threads (4 waves/block).
// ---------------------------------------------------------------------------
__global__ __launch_bounds__(256) void norm_k_kernel(float* __restrict__ kvqz) {
  const int wid  = (blockIdx.x * 256 + threadIdx.x) >> 6;  // row index
  const int lane = threadIdx.x & 63;
  float x = kvqz[(size_t)wid * 256 + lane];
  float s = x * x;
  s += __shfl_xor(s, 1);  s += __shfl_xor(s, 2);  s += __shfl_xor(s, 4);
  s += __shfl_xor(s, 8);  s += __shfl_xor(s, 16); s += __shfl_xor(s, 32);
  kvqz[(size_t)wid * 256 + lane] = x / (sqrtf(s) + 1e-6f);
}

// ---------------------------------------------------------------------------
// Sequential delta-rule scan. One block per batch (8 blocks, 256 threads).
// Thread t = r*4 + c owns S[r][c*16 .. c*16+15]. Rows are independent ->
// NO __syncthreads anywhere; reductions are 2 shfl_xor over the 4-lane group.
// Next-step k/v/q/z are prefetched (S-independent) to hide load latency.
// ---------------------------------------------------------------------------
__global__ __launch_bounds__(256) void scan_kernel(
    const float* __restrict__ kvqz, float* __restrict__ ys) {
  const int b   = blockIdx.x;
  const int tid = threadIdx.x;
  const int r   = tid >> 2;       // 0..63 state row
  const int c   = tid & 3;        // 0..3 column group
  const int cb  = c << 4;         // column base
  float S[16];
#pragma unroll
  for (int i = 0; i < 16; ++i) S[i] = 0.f;

  const float* base = kvqz + (size_t)b * 256;  // step stride = BB*256 floats
  float4 nk[4], nq[4];
  float  nv, nz;
  {
    const float* p = base;
#pragma unroll
    for (int i = 0; i < 4; ++i) {
      nk[i] = *(const float4*)&p[cb + 4 * i];
      nq[i] = *(const float4*)&p[128 + cb + 4 * i];
    }
    nv = p[64 + r];
    nz = p[192 + r];
  }

  for (int t = 0; t < TT; ++t) {
    float ka[16] = {nk[0].x, nk[0].y, nk[0].z, nk[0].w,
                    nk[1].x, nk[1].y, nk[1].z, nk[1].w,
                    nk[2].x, nk[2].y, nk[2].z, nk[2].w,
                    nk[3].x, nk[3].y, nk[3].z, nk[3].w};
    float qa[16] = {nq[0].x, nq[0].y, nq[0].z, nq[0].w,
                    nq[1].x, nq[1].y, nq[1].z, nq[1].w,
                    nq[2].x, nq[2].y, nq[2].z, nq[2].w,
                    nq[3].x, nq[3].y, nq[3].z, nq[3].w};
    float vv = nv, zz = nz;

    // prefetch step t+1 (clamped; independent of S)
    const int t1 = (t + 1 < TT) ? t + 1 : t;
    const float* p = base + (size_t)t1 * (BB * 256);
#pragma unroll
    for (int i = 0; i < 4; ++i) {
      nk[i] = *(const float4*)&p[cb + 4 * i];
      nq[i] = *(const float4*)&p[128 + cb + 4 * i];
    }
    nv = p[64 + r];
    nz = p[192 + r];

    // pred[r] = S[r,:] . k   (4 parallel chains + 4-lane reduce)
    float p0 = 0.f, p1 = 0.f, p2 = 0.f, p3 = 0.f;
#pragma unroll
    for (int i = 0; i < 4; ++i) {
      p0 = fmaf(S[4 * i + 0], ka[4 * i + 0], p0);
      p1 = fmaf(S[4 * i + 1], ka[4 * i + 1], p1);
      p2 = fmaf(S[4 * i + 2], ka[4 * i + 2], p2);
      p3 = fmaf(S[4 * i + 3], ka[4 * i + 3], p3);
    }
    float pr = (p0 + p1) + (p2 + p3);
    pr += __shfl_xor(pr, 1);
    pr += __shfl_xor(pr, 2);
    const float err = vv - pr;

    // S[r,:] += err * k ; y[r] = S_new[r,:] . q
    float y0 = 0.f, y1 = 0.f, y2 = 0.f, y3 = 0.f;
#pragma unroll
    for (int i = 0; i < 4; ++i) {
      S[4 * i + 0] = fmaf(err, ka[4 * i + 0], S[4 * i + 0]);
      S[4 * i + 1] = fmaf(err, ka[4 * i + 1], S[4 * i + 1]);
      S[4 * i + 2] = fmaf(err, ka[4 * i + 2], S[4 * i + 2]);
      S[4 * i + 3] = fmaf(err, ka[4 * i + 3], S[4 * i + 3]);
      y0 = fmaf(S[4 * i + 0], qa[4 * i + 0], y0);
      y1 = fmaf(S[4 * i + 1], qa[4 * i + 1], y1);
      y2 = fmaf(S[4 * i + 2], qa[4 * i + 2], y2);
      y3 = fmaf(S[4 * i + 3], qa[4 * i + 3], y3);
    }
    float yr = (y0 + y1) + (y2 + y3);
    yr += __shfl_xor(yr, 1);
    yr += __shfl_xor(yr, 2);

    if (c == 0) {
      float e2 = __expf(2.f * yr);
      float th = 1.f - 2.f / (e2 + 1.f);          // tanh
      float sg = 1.f / (1.f + __expf(-zz));       // sigmoid
      ys[((size_t)t * BB + b) * NS_ + r] = th * sg;
    }
  }
}

// ---------------------------------------------------------------------------
extern "C" void kernel_launch(void* const* d_in, const int* in_sizes, int n_in,
                              void* d_out, int out_size, void* d_ws, size_t ws_size,
                              hipStream_t stream) {
  const float* x    = (const float*)d_in[0];  // [T,B,DIM]
  const float* Win  = (const float*)d_in[1];  // [DI,DIM]
  const float* Wk   = (const float*)d_in[2];  // [NS,DI]
  const float* Wv   = (const float*)d_in[3];
  const float* Wq   = (const float*)d_in[4];
  const float* Wz   = (const float*)d_in[5];
  const float* Wout = (const float*)d_in[6];  // [DIM,NS]
  float* out = (float*)d_out;                 // [T,B,DIM]

  char* ws = (char*)d_ws;
  float* Wf   = (float*)(ws);                         // 256x1024   (1 MB)
  float* kvqz = (float*)(ws + (1u << 20));            // 16384x256  (16 MB)
  float* ys   = (float*)(ws + (17u << 20));           // 16384x64   (4 MB)

  // 1. fused projection weight: Wf = [Wk;Wv;Wq;Wz] * Win   (256x1024)
  fuse_w_kernel<<<dim3(DIM_ / 256, 64), 256, 0, stream>>>(Wk, Wv, Wq, Wz, Win, Wf);

  // 2. kvqz = x * Wf^T   [16384, 256]
  gemm_abt<<<dim3(256 / 128, MR_ / 128), 256, 0, stream>>>(x, Wf, kvqz, MR_, 256, DIM_);

  // 3. unit-normalize k rows
  norm_k_kernel<<<MR_ / 4, 256, 0, stream>>>(kvqz);

  // 4. sequential delta-rule scan -> ys [16384, 64]
  scan_kernel<<<BB, 256, 0, stream>>>(kvqz, ys);

  // 5. out = ys * Wout^T   [16384, 1024]
  gemm_abt<<<dim3(DIM_ / 128, MR_ / 128), 256, 0, stream>>>(ys, Wout, out, MR_, DIM_, NS_);
}

// Round 2
// 633.061 us; speedup vs baseline: 3.3576x; 3.3576x over previous
//
#include <hip/hip_runtime.h>
#include <math.h>

#define TT   2048
#define BB   8
#define DIM_ 1024
#define DI_  2048
#define NS_  64
#define MR_  (TT * BB)   // 16384 rows (t-major, b-minor)
#define NCH  32          // chunks of 64 steps
#define LD   68          // padded LDS leading dim (16B-aligned rows)

__device__ __forceinline__ float dot4(float4 a, float4 b) {
  return a.x * b.x + a.y * b.y + a.z * b.z + a.w * b.w;
}

// ---------------------------------------------------------------------------
// Wf[n][d] = sum_i W*[n][i] * W_in[i][d]  for n in [0,256)
// ---------------------------------------------------------------------------
__global__ __launch_bounds__(256) void fuse_w_kernel(
    const float* __restrict__ Wk, const float* __restrict__ Wv,
    const float* __restrict__ Wq, const float* __restrict__ Wz,
    const float* __restrict__ Win, float* __restrict__ Wf) {
  const int d  = blockIdx.x * 256 + threadIdx.x;
  const int n0 = blockIdx.y;  // 0..63
  const float* rk = Wk + (size_t)n0 * DI_;
  const float* rv = Wv + (size_t)n0 * DI_;
  const float* rq = Wq + (size_t)n0 * DI_;
  const float* rz = Wz + (size_t)n0 * DI_;
  float a0 = 0.f, a1 = 0.f, a2 = 0.f, a3 = 0.f;
#pragma unroll 4
  for (int i = 0; i < DI_; ++i) {
    float w = Win[(size_t)i * DIM_ + d];
    a0 = fmaf(rk[i], w, a0);
    a1 = fmaf(rv[i], w, a1);
    a2 = fmaf(rq[i], w, a2);
    a3 = fmaf(rz[i], w, a3);
  }
  Wf[(size_t)(n0      ) * DIM_ + d] = a0;
  Wf[(size_t)(n0 +  64) * DIM_ + d] = a1;
  Wf[(size_t)(n0 + 128) * DIM_ + d] = a2;
  Wf[(size_t)(n0 + 192) * DIM_ + d] = a3;
}

// ---------------------------------------------------------------------------
// fp32 tiled GEMM:  C[M,N] = A[M,K] * B[N,K]^T
// ---------------------------------------------------------------------------
__global__ __launch_bounds__(256) void gemm_abt(
    const float* __restrict__ A, const float* __restrict__ B,
    float* __restrict__ C, int M, int N, int K) {
  __shared__ __align__(16) float As[16][132];
  __shared__ __align__(16) float Bs[16][132];
  const int tid  = threadIdx.x;
  const int m0   = blockIdx.y * 128;
  const int n0   = blockIdx.x * 128;
  const int lrow = tid >> 2;
  const int lk4  = (tid & 3) << 2;
  const int tm   = (tid & 15) << 2;
  const int tn   = (tid >> 4) << 2;
  float acc[8][8];
#pragma unroll
  for (int i = 0; i < 8; ++i)
#pragma unroll
    for (int j = 0; j < 8; ++j) acc[i][j] = 0.f;

  for (int k0 = 0; k0 < K; k0 += 16) {
    float4 av0 = *(const float4*)&A[(size_t)(m0 + lrow)      * K + k0 + lk4];
    float4 av1 = *(const float4*)&A[(size_t)(m0 + 64 + lrow) * K + k0 + lk4];
    float4 bv0 = *(const float4*)&B[(size_t)(n0 + lrow)      * K + k0 + lk4];
    float4 bv1 = *(const float4*)&B[(size_t)(n0 + 64 + lrow) * K + k0 + lk4];
    __syncthreads();
    As[lk4 + 0][lrow] = av0.x; As[lk4 + 1][lrow] = av0.y;
    As[lk4 + 2][lrow] = av0.z; As[lk4 + 3][lrow] = av0.w;
    As[lk4 + 0][64 + lrow] = av1.x; As[lk4 + 1][64 + lrow] = av1.y;
    As[lk4 + 2][64 + lrow] = av1.z; As[lk4 + 3][64 + lrow] = av1.w;
    Bs[lk4 + 0][lrow] = bv0.x; Bs[lk4 + 1][lrow] = bv0.y;
    Bs[lk4 + 2][lrow] = bv0.z; Bs[lk4 + 3][lrow] = bv0.w;
    Bs[lk4 + 0][64 + lrow] = bv1.x; Bs[lk4 + 1][64 + lrow] = bv1.y;
    Bs[lk4 + 2][64 + lrow] = bv1.z; Bs[lk4 + 3][64 + lrow] = bv1.w;
    __syncthreads();
#pragma unroll
    for (int kk = 0; kk < 16; ++kk) {
      float4 a0 = *(const float4*)&As[kk][tm];
      float4 a1 = *(const float4*)&As[kk][tm + 64];
      float4 b0 = *(const float4*)&Bs[kk][tn];
      float4 b1 = *(const float4*)&Bs[kk][tn + 64];
      float ar[8] = {a0.x, a0.y, a0.z, a0.w, a1.x, a1.y, a1.z, a1.w};
      float br[8] = {b0.x, b0.y, b0.z, b0.w, b1.x, b1.y, b1.z, b1.w};
#pragma unroll
      for (int i = 0; i < 8; ++i)
#pragma unroll
        for (int j = 0; j < 8; ++j)
          acc[i][j] = fmaf(ar[i], br[j], acc[i][j]);
    }
  }
#pragma unroll
  for (int i = 0; i < 8; ++i) {
    int r = m0 + tm + (i & 3) + ((i >> 2) << 6);
    float4 c0 = make_float4(acc[i][0], acc[i][1], acc[i][2], acc[i][3]);
    float4 c1 = make_float4(acc[i][4], acc[i][5], acc[i][6], acc[i][7]);
    *(float4*)&C[(size_t)r * N + n0 + tn]      = c0;
    *(float4*)&C[(size_t)r * N + n0 + tn + 64] = c1;
  }
}

// ---------------------------------------------------------------------------
// Unit-normalize each k row (first 64 cols of kvqz).
// ---------------------------------------------------------------------------
__global__ __launch_bounds__(256) void norm_k_kernel(float* __restrict__ kvqz) {
  const int wid  = (blockIdx.x * 256 + threadIdx.x) >> 6;
  const int lane = threadIdx.x & 63;
  float x = kvqz[(size_t)wid * 256 + lane];
  float s = x * x;
  s += __shfl_xor(s, 1);  s += __shfl_xor(s, 2);  s += __shfl_xor(s, 4);
  s += __shfl_xor(s, 8);  s += __shfl_xor(s, 16); s += __shfl_xor(s, 32);
  kvqz[(size_t)wid * 256 + lane] = x / (sqrtf(s) + 1e-6f);
}

// ---------------------------------------------------------------------------
// Phase 1 (parallel over 256 chunk-batch units):
//   A = K K^T ; Tt = inv(I + stril(A)) stored transposed (Tt[j][i]=T[i][j]);
//   P = T K ; Pv = T V ; M = I - P^T K ; B = Pv^T K.
//   Store Tt, M, B to global.
// ---------------------------------------------------------------------------
__global__ __launch_bounds__(256) void phase1_kernel(
    const float* __restrict__ kvqz, float* __restrict__ Tg,
    float* __restrict__ Mg, float* __restrict__ Bg) {
  __shared__ __align__(16) float Ks[64][LD];
  __shared__ __align__(16) float Vs[64][LD];
  __shared__ __align__(16) float As[64][LD];   // A, later reused as P
  __shared__ __align__(16) float Tt[64][LD];
  __shared__ __align__(16) float Pv[64][LD];
  const int cb = blockIdx.x;
  const int c  = cb >> 3, b = cb & 7;
  const int t  = threadIdx.x;

  {  // load K, V chunk
    const int tau = t >> 2, m0 = (t & 3) << 4;
    const float* src = kvqz + (size_t)((c * 64 + tau) * BB + b) * 256;
#pragma unroll
    for (int u = 0; u < 4; ++u) {
      *(float4*)&Ks[tau][m0 + 4 * u] = *(const float4*)&src[m0 + 4 * u];
      *(float4*)&Vs[tau][m0 + 4 * u] = *(const float4*)&src[64 + m0 + 4 * u];
    }
  }
  __syncthreads();

  const int i0 = (t >> 4) << 2;
  const int j0 = (t & 15) << 2;

  {  // A = K K^T
    float acc[4][4];
#pragma unroll
    for (int i = 0; i < 4; ++i)
#pragma unroll
      for (int j = 0; j < 4; ++j) acc[i][j] = 0.f;
    for (int m4 = 0; m4 < 64; m4 += 4) {
      float4 ar[4], br[4];
#pragma unroll
      for (int i = 0; i < 4; ++i) ar[i] = *(const float4*)&Ks[i0 + i][m4];
#pragma unroll
      for (int j = 0; j < 4; ++j) br[j] = *(const float4*)&Ks[j0 + j][m4];
#pragma unroll
      for (int i = 0; i < 4; ++i)
#pragma unroll
        for (int j = 0; j < 4; ++j) acc[i][j] += dot4(ar[i], br[j]);
    }
#pragma unroll
    for (int i = 0; i < 4; ++i)
      *(float4*)&As[i0 + i][j0] =
          make_float4(acc[i][0], acc[i][1], acc[i][2], acc[i][3]);
  }
  __syncthreads();

  // wave 0: column-parallel forward substitution, transposed storage.
  if (t < 64) {
    const int j = t;
    Tt[j][0] = (j == 0) ? 1.f : 0.f;
    for (int i = 1; i < 64; ++i) {
      float acc = 0.f;
      const int nf = i >> 2;
      for (int s4 = 0; s4 < nf; ++s4) {
        float4 av = *(const float4*)&As[i][4 * s4];
        float4 tv = *(const float4*)&Tt[j][4 * s4];
        acc += dot4(av, tv);
      }
      for (int s = 4 * nf; s < i; ++s) acc = fmaf(As[i][s], Tt[j][s], acc);
      Tt[j][i] = (i == j) ? 1.f : -acc;
    }
  }
  __syncthreads();

  {  // P = T K -> As (overwrite A) ; Pv = T V
    float accP[4][4], accV[4][4];
#pragma unroll
    for (int i = 0; i < 4; ++i)
#pragma unroll
      for (int j = 0; j < 4; ++j) { accP[i][j] = 0.f; accV[i][j] = 0.f; }
    for (int s = 0; s < 64; ++s) {
      float4 tv = *(const float4*)&Tt[s][i0];
      float4 kv = *(const float4*)&Ks[s][j0];
      float4 vv = *(const float4*)&Vs[s][j0];
      float ta[4] = {tv.x, tv.y, tv.z, tv.w};
      float ka[4] = {kv.x, kv.y, kv.z, kv.w};
      float va[4] = {vv.x, vv.y, vv.z, vv.w};
#pragma unroll
      for (int i = 0; i < 4; ++i)
#pragma unroll
        for (int j = 0; j < 4; ++j) {
          accP[i][j] = fmaf(ta[i], ka[j], accP[i][j]);
          accV[i][j] = fmaf(ta[i], va[j], accV[i][j]);
        }
    }
    __syncthreads();  // everyone done reading old As content (solve) -- safe by order anyway
#pragma unroll
    for (int i = 0; i < 4; ++i) {
      *(float4*)&As[i0 + i][j0] =
          make_float4(accP[i][0], accP[i][1], accP[i][2], accP[i][3]);
      *(float4*)&Pv[i0 + i][j0] =
          make_float4(accV[i][0], accV[i][1], accV[i][2], accV[i][3]);
    }
  }
  __syncthreads();

  {  // M = I - P^T K ; B = Pv^T K  -> global
    float accM[4][4], accB[4][4];
#pragma unroll
    for (int i = 0; i < 4; ++i)
#pragma unroll
      for (int j = 0; j < 4; ++j) { accM[i][j] = 0.f; accB[i][j] = 0.f; }
    for (int s = 0; s < 64; ++s) {
      float4 pv  = *(const float4*)&As[s][i0];
      float4 pvv = *(const float4*)&Pv[s][i0];
      float4 kv  = *(const float4*)&Ks[s][j0];
      float pa[4] = {pv.x, pv.y, pv.z, pv.w};
      float qa[4] = {pvv.x, pvv.y, pvv.z, pvv.w};
      float ka[4] = {kv.x, kv.y, kv.z, kv.w};
#pragma unroll
      for (int i = 0; i < 4; ++i)
#pragma unroll
        for (int j = 0; j < 4; ++j) {
          accM[i][j] = fmaf(pa[i], ka[j], accM[i][j]);
          accB[i][j] = fmaf(qa[i], ka[j], accB[i][j]);
        }
    }
    const size_t base = (size_t)cb * 4096;
#pragma unroll
    for (int i = 0; i < 4; ++i) {
      float m0v = ((i0 + i) == (j0 + 0)) ? 1.f : 0.f;
      float m1v = ((i0 + i) == (j0 + 1)) ? 1.f : 0.f;
      float m2v = ((i0 + i) == (j0 + 2)) ? 1.f : 0.f;
      float m3v = ((i0 + i) == (j0 + 3)) ? 1.f : 0.f;
      *(float4*)&Mg[base + (size_t)(i0 + i) * 64 + j0] =
          make_float4(m0v - accM[i][0], m1v - accM[i][1],
                      m2v - accM[i][2], m3v - accM[i][3]);
      *(float4*)&Bg[base + (size_t)(i0 + i) * 64 + j0] =
          make_float4(accB[i][0], accB[i][1], accB[i][2], accB[i][3]);
    }
    // store Tt (transposed layout) flat
    const int fr = t >> 2, fc = (t & 3) << 4;
#pragma unroll
    for (int u = 0; u < 4; ++u)
      *(float4*)&Tg[base + (size_t)fr * 64 + fc + 4 * u] =
          *(const float4*)&Tt[fr][fc + 4 * u];
  }
}

// ---------------------------------------------------------------------------
// Phase 2 (serial over 32 chunks, parallel over 8 batches):
//   Sall[c] = S_{c-1};  S_c = S_{c-1} * M_c + B_c,  S_{-1}... S starts 0.
// ---------------------------------------------------------------------------
__global__ __launch_bounds__(256) void phase2_kernel(
    const float* __restrict__ Mg, const float* __restrict__ Bg,
    float* __restrict__ Sall) {
  __shared__ __align__(16) float Ss[64][LD];
  __shared__ __align__(16) float Ms[64][LD];
  const int b = blockIdx.x;
  const int t = threadIdx.x;
  const int i0 = (t >> 4) << 2;   // n rows
  const int j0 = (t & 15) << 2;   // m cols
  const int fr = t >> 2;          // M staging row
  const int fc = (t & 3) << 4;    // M staging col base

  float ns[4][4];
#pragma unroll
  for (int i = 0; i < 4; ++i)
#pragma unroll
    for (int j = 0; j < 4; ++j) ns[i][j] = 0.f;

  float4 pm[4];
  {
    const float* mp = Mg + (size_t)b * 4096 + (size_t)fr * 64 + fc;
#pragma unroll
    for (int u = 0; u < 4; ++u) pm[u] = *(const float4*)&mp[4 * u];
  }

  for (int c = 0; c < NCH; ++c) {
    const size_t cbase = (size_t)(c * BB + b) * 4096;
    // publish state (pre-chunk) + stage M_c
#pragma unroll
    for (int i = 0; i < 4; ++i) {
      float4 row = make_float4(ns[i][0], ns[i][1], ns[i][2], ns[i][3]);
      *(float4*)&Sall[cbase + (size_t)(i0 + i) * 64 + j0] = row;
      *(float4*)&Ss[i0 + i][j0] = row;
    }
#pragma unroll
    for (int u = 0; u < 4; ++u) *(float4*)&Ms[fr][fc + 4 * u] = pm[u];
    __syncthreads();

    // prefetch M_{c+1}, load B_c (consumed after the compute loop)
    if (c + 1 < NCH) {
      const float* mp = Mg + (size_t)((c + 1) * BB + b) * 4096 + (size_t)fr * 64 + fc;
#pragma unroll
      for (int u = 0; u < 4; ++u) pm[u] = *(const float4*)&mp[4 * u];
    }
    float4 bv[4];
#pragma unroll
    for (int i = 0; i < 4; ++i)
      bv[i] = *(const float4*)&Bg[cbase + (size_t)(i0 + i) * 64 + j0];

    float acc[4][4];
#pragma unroll
    for (int i = 0; i < 4; ++i)
#pragma unroll
      for (int j = 0; j < 4; ++j) acc[i][j] = 0.f;
    for (int m4 = 0; m4 < 64; m4 += 4) {
      float4 sv[4], mv[4];
#pragma unroll
      for (int i = 0; i < 4; ++i) sv[i] = *(const float4*)&Ss[i0 + i][m4];
#pragma unroll
      for (int j2 = 0; j2 < 4; ++j2) mv[j2] = *(const float4*)&Ms[m4 + j2][j0];
      float ma[4][4] = {{mv[0].x, mv[0].y, mv[0].z, mv[0].w},
                        {mv[1].x, mv[1].y, mv[1].z, mv[1].w},
                        {mv[2].x, mv[2].y, mv[2].z, mv[2].w},
                        {mv[3].x, mv[3].y, mv[3].z, mv[3].w}};
#pragma unroll
      for (int i = 0; i < 4; ++i) {
        float sa[4] = {sv[i].x, sv[i].y, sv[i].z, sv[i].w};
#pragma unroll
        for (int j = 0; j < 4; ++j)
          acc[i][j] += sa[0] * ma[0][j] + sa[1] * ma[1][j] +
                       sa[2] * ma[2][j] + sa[3] * ma[3][j];
      }
    }
    float ba[4][4] = {{bv[0].x, bv[0].y, bv[0].z, bv[0].w},
                      {bv[1].x, bv[1].y, bv[1].z, bv[1].w},
                      {bv[2].x, bv[2].y, bv[2].z, bv[2].w},
                      {bv[3].x, bv[3].y, bv[3].z, bv[3].w}};
#pragma unroll
    for (int i = 0; i < 4; ++i)
#pragma unroll
      for (int j = 0; j < 4; ++j) ns[i][j] = acc[i][j] + ba[i][j];
    __syncthreads();  // all reads of Ss/Ms done before next iteration's writes
  }
}

// ---------------------------------------------------------------------------
// Phase 3 (parallel over 256 chunk-batch units):
//   Gt = (Q K^T)^T ; W = V - K S0^T ; U = T W ;
//   Y = Q S0^T + tril(G) U ; y = tanh(Y) * sigmoid(Z)  -> ys
// ---------------------------------------------------------------------------
__global__ __launch_bounds__(256) void phase3_kernel(
    const float* __restrict__ kvqz, const float* __restrict__ Tg,
    const float* __restrict__ Sall, float* __restrict__ ys) {
  __shared__ __align__(16) float Ks[64][LD];
  __shared__ __align__(16) float Qs[64][LD];
  __shared__ __align__(16) float S0s[64][LD];
  __shared__ __align__(16) float Tts[64][LD];
  __shared__ __align__(16) float Gts[64][LD];
  __shared__ __align__(16) float Ws[64][LD];
  __shared__ __align__(16) float Us[64][LD];
  const int cb = blockIdx.x;
  const int c  = cb >> 3, b = cb & 7;
  const int t  = threadIdx.x;
  const size_t base = (size_t)cb * 4096;

  {
    const int tau = t >> 2, m0 = (t & 3) << 4;
    const float* src = kvqz + (size_t)((c * 64 + tau) * BB + b) * 256;
#pragma unroll
    for (int u = 0; u < 4; ++u) {
      *(float4*)&Ks[tau][m0 + 4 * u]  = *(const float4*)&src[m0 + 4 * u];
      *(float4*)&Qs[tau][m0 + 4 * u]  = *(const float4*)&src[128 + m0 + 4 * u];
      *(float4*)&S0s[tau][m0 + 4 * u] = *(const float4*)&Sall[base + (size_t)tau * 64 + m0 + 4 * u];
      *(float4*)&Tts[tau][m0 + 4 * u] = *(const float4*)&Tg[base + (size_t)tau * 64 + m0 + 4 * u];
    }
  }
  __syncthreads();

  const int i0 = (t >> 4) << 2;
  const int j0 = (t & 15) << 2;

  {  // Gt[s][tq] = sum_m K[s][m] Q[tq][m]   (tile: s=i0 rows, tq=j0 cols)
    float acc[4][4];
#pragma unroll
    for (int i = 0; i < 4; ++i)
#pragma unroll
      for (int j = 0; j < 4; ++j) acc[i][j] = 0.f;
    for (int m4 = 0; m4 < 64; m4 += 4) {
      float4 kr[4], qr[4];
#pragma unroll
      for (int i = 0; i < 4; ++i) kr[i] = *(const float4*)&Ks[i0 + i][m4];
#pragma unroll
      for (int j = 0; j < 4; ++j) qr[j] = *(const float4*)&Qs[j0 + j][m4];
#pragma unroll
      for (int i = 0; i < 4; ++i)
#pragma unroll
        for (int j = 0; j < 4; ++j) acc[i][j] += dot4(kr[i], qr[j]);
    }
#pragma unroll
    for (int i = 0; i < 4; ++i)
      *(float4*)&Gts[i0 + i][j0] =
          make_float4(acc[i][0], acc[i][1], acc[i][2], acc[i][3]);
  }

  {  // W[tau][n] = V[tau][n] - sum_m K[tau][m] S0[n][m]  (tau=i0, n=j0)
    float acc[4][4];
#pragma unroll
    for (int i = 0; i < 4; ++i) {
      const float* vrow = kvqz + (size_t)((c * 64 + i0 + i) * BB + b) * 256 + 64;
      float4 vv = *(const float4*)&vrow[j0];
      acc[i][0] = vv.x; acc[i][1] = vv.y; acc[i][2] = vv.z; acc[i][3] = vv.w;
    }
    for (int m4 = 0; m4 < 64; m4 += 4) {
      float4 kr[4], sr[4];
#pragma unroll
      for (int i = 0; i < 4; ++i) kr[i] = *(const float4*)&Ks[i0 + i][m4];
#pragma unroll
      for (int j = 0; j < 4; ++j) sr[j] = *(const float4*)&S0s[j0 + j][m4];
#pragma unroll
      for (int i = 0; i < 4; ++i)
#pragma unroll
        for (int j = 0; j < 4; ++j) acc[i][j] -= dot4(kr[i], sr[j]);
    }
    __syncthreads();  // Gts fully written too before anyone reads it later
#pragma unroll
    for (int i = 0; i < 4; ++i)
      *(float4*)&Ws[i0 + i][j0] =
          make_float4(acc[i][0], acc[i][1], acc[i][2], acc[i][3]);
  }
  __syncthreads();

  float4 zv[4];
  {  // U[tq][n] = sum_s Tt[s][tq] W[s][n]  (tq=i0, n=j0); prefetch Z tile
#pragma unroll
    for (int i = 0; i < 4; ++i) {
      const float* zrow = kvqz + (size_t)((c * 64 + i0 + i) * BB + b) * 256 + 192;
      zv[i] = *(const float4*)&zrow[j0];
    }
    float acc[4][4];
#pragma unroll
    for (int i = 0; i < 4; ++i)
#pragma unroll
      for (int j = 0; j < 4; ++j) acc[i][j] = 0.f;
    for (int s = 0; s < 64; ++s) {
      float4 tv = *(const float4*)&Tts[s][i0];
      float4 wv = *(const float4*)&Ws[s][j0];
      float ta[4] = {tv.x, tv.y, tv.z, tv.w};
      float wa[4] = {wv.x, wv.y, wv.z, wv.w};
#pragma unroll
      for (int i = 0; i < 4; ++i)
#pragma unroll
        for (int j = 0; j < 4; ++j) acc[i][j] = fmaf(ta[i], wa[j], acc[i][j]);
    }
    __syncthreads();
#pragma unroll
    for (int i = 0; i < 4; ++i)
      *(float4*)&Us[i0 + i][j0] =
          make_float4(acc[i][0], acc[i][1], acc[i][2], acc[i][3]);
  }
  __syncthreads();

  {  // Y = Q S0^T + tril(G) U ; out
    float acc[4][4];
#pragma unroll
    for (int i = 0; i < 4; ++i)
#pragma unroll
      for (int j = 0; j < 4; ++j) acc[i][j] = 0.f;
    for (int m4 = 0; m4 < 64; m4 += 4) {
      float4 qr[4], sr[4];
#pragma unroll
      for (int i = 0; i < 4; ++i) qr[i] = *(const float4*)&Qs[i0 + i][m4];
#pragma unroll
      for (int j = 0; j < 4; ++j) sr[j] = *(const float4*)&S0s[j0 + j][m4];
#pragma unroll
      for (int i = 0; i < 4; ++i)
#pragma unroll
        for (int j = 0; j < 4; ++j) acc[i][j] += dot4(qr[i], sr[j]);
    }
    for (int s = 0; s < 64; ++s) {
      float4 gv = *(const float4*)&Gts[s][i0];
      float4 uv = *(const float4*)&Us[s][j0];
      float ga[4] = {gv.x, gv.y, gv.z, gv.w};
      float ua[4] = {uv.x, uv.y, uv.z, uv.w};
#pragma unroll
      for (int i = 0; i < 4; ++i) {
        float gi = (s <= i0 + i) ? ga[i] : 0.f;
#pragma unroll
        for (int j = 0; j < 4; ++j) acc[i][j] = fmaf(gi, ua[j], acc[i][j]);
      }
    }
#pragma unroll
    for (int i = 0; i < 4; ++i) {
      float za[4] = {zv[i].x, zv[i].y, zv[i].z, zv[i].w};
      float4 o;
      float* op = &o.x;
#pragma unroll
      for (int j = 0; j < 4; ++j) {
        float e2 = __expf(2.f * acc[i][j]);
        float th = 1.f - 2.f / (e2 + 1.f);
        float sg = 1.f / (1.f + __expf(-za[j]));
        op[j] = th * sg;
      }
      *(float4*)&ys[(size_t)((c * 64 + i0 + i) * BB + b) * 64 + j0] = o;
    }
  }
}

// ---------------------------------------------------------------------------
extern "C" void kernel_launch(void* const* d_in, const int* in_sizes, int n_in,
                              void* d_out, int out_size, void* d_ws, size_t ws_size,
                              hipStream_t stream) {
  const float* x    = (const float*)d_in[0];
  const float* Win  = (const float*)d_in[1];
  const float* Wk   = (const float*)d_in[2];
  const float* Wv   = (const float*)d_in[3];
  const float* Wq   = (const float*)d_in[4];
  const float* Wz   = (const float*)d_in[5];
  const float* Wout = (const float*)d_in[6];
  float* out = (float*)d_out;

  char* ws = (char*)d_ws;
  float* Wf   = (float*)(ws);                  // 1 MB
  float* kvqz = (float*)(ws + (1u  << 20));    // 16 MB
  float* ys   = (float*)(ws + (17u << 20));    // 4 MB
  float* Tg   = (float*)(ws + (21u << 20));    // 4 MB
  float* Mg   = (float*)(ws + (25u << 20));    // 4 MB
  float* Bg   = (float*)(ws + (29u << 20));    // 4 MB
  float* Sall = (float*)(ws + (33u << 20));    // 4 MB  (37 MB total)

  fuse_w_kernel<<<dim3(DIM_ / 256, 64), 256, 0, stream>>>(Wk, Wv, Wq, Wz, Win, Wf);
  gemm_abt<<<dim3(256 / 128, MR_ / 128), 256, 0, stream>>>(x, Wf, kvqz, MR_, 256, DIM_);
  norm_k_kernel<<<MR_ / 4, 256, 0, stream>>>(kvqz);
  phase1_kernel<<<NCH * BB, 256, 0, stream>>>(kvqz, Tg, Mg, Bg);
  phase2_kernel<<<BB, 256, 0, stream>>>(Mg, Bg, Sall);
  phase3_kernel<<<NCH * BB, 256, 0, stream>>>(kvqz, Tg, Sall, ys);
  gemm_abt<<<dim3(DIM_ / 128, MR_ / 128), 256, 0, stream>>>(ys, Wout, out, MR_, DIM_, NS_);
}

// Round 3
// 503.886 us; speedup vs baseline: 4.2184x; 1.2564x over previous
//
#include <hip/hip_runtime.h>
#include <math.h>

#define TT   2048
#define BB   8
#define DIM_ 1024
#define DI_  2048
#define NS_  64
#define MR_  (TT * BB)   // 16384 rows (t-major, b-minor)
#define NCH  32          // chunks of 64 steps
#define LD   68          // padded LDS leading dim (16B-aligned rows)
#define KSPL 16          // split-K factor for fuse GEMM
#define KCH  (DI_ / KSPL)

__device__ __forceinline__ float dot4(float4 a, float4 b) {
  return a.x * b.x + a.y * b.y + a.z * b.z + a.w * b.w;
}

// ---------------------------------------------------------------------------
// fuse GEMM (split-K): Pg[ks] partial of Wf[256][1024] = Wg[256][2048]*Win[2048][1024]
// Wg rows 0..63=W_k, 64..127=W_v, 128..191=W_q, 192..255=W_z (gathered by ptr).
// grid (N/128, M/128, KSPL), 256 threads, 128x128 tile, BK=16, 8x8 microtile.
// ---------------------------------------------------------------------------
__global__ __launch_bounds__(256) void fuse_gemm_kernel(
    const float* __restrict__ Wk, const float* __restrict__ Wv,
    const float* __restrict__ Wq, const float* __restrict__ Wz,
    const float* __restrict__ Win, float* __restrict__ Pg) {
  __shared__ __align__(16) float As[16][132];
  __shared__ __align__(16) float Bs[16][132];
  const int tid = threadIdx.x;
  const int n0  = blockIdx.x * 128;   // over DIM_ (N=1024)
  const int m0  = blockIdx.y * 128;   // over fused rows (M=256)
  const int kb  = blockIdx.z * KCH;   // K split base
  const int lrow = tid >> 2;
  const int lk4  = (tid & 3) << 2;
  const int tm   = (tid & 15) << 2;
  const int tn   = (tid >> 4) << 2;
  const float* Wg[4] = {Wk, Wv, Wq, Wz};
  const int ra = m0 + lrow, rb = m0 + 64 + lrow;
  const float* arow0 = Wg[ra >> 6] + (size_t)(ra & 63) * DI_;
  const float* arow1 = Wg[rb >> 6] + (size_t)(rb & 63) * DI_;
  const int brow = tid >> 5;          // 0..7
  const int bcol = (tid & 31) << 2;   // 0..124

  float acc[8][8];
#pragma unroll
  for (int i = 0; i < 8; ++i)
#pragma unroll
    for (int j = 0; j < 8; ++j) acc[i][j] = 0.f;

  for (int k0 = 0; k0 < KCH; k0 += 16) {
    float4 av0 = *(const float4*)&arow0[kb + k0 + lk4];
    float4 av1 = *(const float4*)&arow1[kb + k0 + lk4];
    float4 bv0 = *(const float4*)&Win[(size_t)(kb + k0 + brow)     * DIM_ + n0 + bcol];
    float4 bv1 = *(const float4*)&Win[(size_t)(kb + k0 + 8 + brow) * DIM_ + n0 + bcol];
    __syncthreads();
    As[lk4 + 0][lrow] = av0.x; As[lk4 + 1][lrow] = av0.y;
    As[lk4 + 2][lrow] = av0.z; As[lk4 + 3][lrow] = av0.w;
    As[lk4 + 0][64 + lrow] = av1.x; As[lk4 + 1][64 + lrow] = av1.y;
    As[lk4 + 2][64 + lrow] = av1.z; As[lk4 + 3][64 + lrow] = av1.w;
    *(float4*)&Bs[brow][bcol]     = bv0;
    *(float4*)&Bs[brow + 8][bcol] = bv1;
    __syncthreads();
#pragma unroll
    for (int kk = 0; kk < 16; ++kk) {
      float4 a0 = *(const float4*)&As[kk][tm];
      float4 a1 = *(const float4*)&As[kk][tm + 64];
      float4 b0 = *(const float4*)&Bs[kk][tn];
      float4 b1 = *(const float4*)&Bs[kk][tn + 64];
      float ar[8] = {a0.x, a0.y, a0.z, a0.w, a1.x, a1.y, a1.z, a1.w};
      float br[8] = {b0.x, b0.y, b0.z, b0.w, b1.x, b1.y, b1.z, b1.w};
#pragma unroll
      for (int i = 0; i < 8; ++i)
#pragma unroll
        for (int j = 0; j < 8; ++j)
          acc[i][j] = fmaf(ar[i], br[j], acc[i][j]);
    }
  }
  float* P = Pg + (size_t)blockIdx.z * (256 * DIM_);
#pragma unroll
  for (int i = 0; i < 8; ++i) {
    int r = m0 + tm + (i & 3) + ((i >> 2) << 6);
    float4 c0 = make_float4(acc[i][0], acc[i][1], acc[i][2], acc[i][3]);
    float4 c1 = make_float4(acc[i][4], acc[i][5], acc[i][6], acc[i][7]);
    *(float4*)&P[(size_t)r * DIM_ + n0 + tn]      = c0;
    *(float4*)&P[(size_t)r * DIM_ + n0 + tn + 64] = c1;
  }
}

// Wf[i] = sum_ks Pg[ks][i]  (float4-wide)
__global__ __launch_bounds__(256) void fuse_reduce_kernel(
    const float* __restrict__ Pg, float* __restrict__ Wf) {
  const size_t i = ((size_t)blockIdx.x * 256 + threadIdx.x) << 2;
  float4 s = *(const float4*)&Pg[i];
#pragma unroll
  for (int ks = 1; ks < KSPL; ++ks) {
    float4 p = *(const float4*)&Pg[(size_t)ks * (256 * DIM_) + i];
    s.x += p.x; s.y += p.y; s.z += p.z; s.w += p.w;
  }
  *(float4*)&Wf[i] = s;
}

// ---------------------------------------------------------------------------
// fp32 tiled GEMM:  C[M,N] = A[M,K] * B[N,K]^T
// ---------------------------------------------------------------------------
__global__ __launch_bounds__(256) void gemm_abt(
    const float* __restrict__ A, const float* __restrict__ B,
    float* __restrict__ C, int M, int N, int K) {
  __shared__ __align__(16) float As[16][132];
  __shared__ __align__(16) float Bs[16][132];
  const int tid  = threadIdx.x;
  const int m0   = blockIdx.y * 128;
  const int n0   = blockIdx.x * 128;
  const int lrow = tid >> 2;
  const int lk4  = (tid & 3) << 2;
  const int tm   = (tid & 15) << 2;
  const int tn   = (tid >> 4) << 2;
  float acc[8][8];
#pragma unroll
  for (int i = 0; i < 8; ++i)
#pragma unroll
    for (int j = 0; j < 8; ++j) acc[i][j] = 0.f;

  for (int k0 = 0; k0 < K; k0 += 16) {
    float4 av0 = *(const float4*)&A[(size_t)(m0 + lrow)      * K + k0 + lk4];
    float4 av1 = *(const float4*)&A[(size_t)(m0 + 64 + lrow) * K + k0 + lk4];
    float4 bv0 = *(const float4*)&B[(size_t)(n0 + lrow)      * K + k0 + lk4];
    float4 bv1 = *(const float4*)&B[(size_t)(n0 + 64 + lrow) * K + k0 + lk4];
    __syncthreads();
    As[lk4 + 0][lrow] = av0.x; As[lk4 + 1][lrow] = av0.y;
    As[lk4 + 2][lrow] = av0.z; As[lk4 + 3][lrow] = av0.w;
    As[lk4 + 0][64 + lrow] = av1.x; As[lk4 + 1][64 + lrow] = av1.y;
    As[lk4 + 2][64 + lrow] = av1.z; As[lk4 + 3][64 + lrow] = av1.w;
    Bs[lk4 + 0][lrow] = bv0.x; Bs[lk4 + 1][lrow] = bv0.y;
    Bs[lk4 + 2][lrow] = bv0.z; Bs[lk4 + 3][lrow] = bv0.w;
    Bs[lk4 + 0][64 + lrow] = bv1.x; Bs[lk4 + 1][64 + lrow] = bv1.y;
    Bs[lk4 + 2][64 + lrow] = bv1.z; Bs[lk4 + 3][64 + lrow] = bv1.w;
    __syncthreads();
#pragma unroll
    for (int kk = 0; kk < 16; ++kk) {
      float4 a0 = *(const float4*)&As[kk][tm];
      float4 a1 = *(const float4*)&As[kk][tm + 64];
      float4 b0 = *(const float4*)&Bs[kk][tn];
      float4 b1 = *(const float4*)&Bs[kk][tn + 64];
      float ar[8] = {a0.x, a0.y, a0.z, a0.w, a1.x, a1.y, a1.z, a1.w};
      float br[8] = {b0.x, b0.y, b0.z, b0.w, b1.x, b1.y, b1.z, b1.w};
#pragma unroll
      for (int i = 0; i < 8; ++i)
#pragma unroll
        for (int j = 0; j < 8; ++j)
          acc[i][j] = fmaf(ar[i], br[j], acc[i][j]);
    }
  }
#pragma unroll
  for (int i = 0; i < 8; ++i) {
    int r = m0 + tm + (i & 3) + ((i >> 2) << 6);
    float4 c0 = make_float4(acc[i][0], acc[i][1], acc[i][2], acc[i][3]);
    float4 c1 = make_float4(acc[i][4], acc[i][5], acc[i][6], acc[i][7]);
    *(float4*)&C[(size_t)r * N + n0 + tn]      = c0;
    *(float4*)&C[(size_t)r * N + n0 + tn + 64] = c1;
  }
}

// ---------------------------------------------------------------------------
// Unit-normalize each k row (first 64 cols of kvqz).
// ---------------------------------------------------------------------------
__global__ __launch_bounds__(256) void norm_k_kernel(float* __restrict__ kvqz) {
  const int wid  = (blockIdx.x * 256 + threadIdx.x) >> 6;
  const int lane = threadIdx.x & 63;
  float x = kvqz[(size_t)wid * 256 + lane];
  float s = x * x;
  s += __shfl_xor(s, 1);  s += __shfl_xor(s, 2);  s += __shfl_xor(s, 4);
  s += __shfl_xor(s, 8);  s += __shfl_xor(s, 16); s += __shfl_xor(s, 32);
  kvqz[(size_t)wid * 256 + lane] = x / (sqrtf(s) + 1e-6f);
}

// ---------------------------------------------------------------------------
// Phase 1 (parallel over 256 chunk-batch units):
//   A = K K^T ; Tt = inv(I + stril(A)) stored transposed; P = T K ; Pv = T V;
//   M = I - P^T K ; B = Pv^T K.  Store Tt, M, B.
// ---------------------------------------------------------------------------
__global__ __launch_bounds__(256) void phase1_kernel(
    const float* __restrict__ kvqz, float* __restrict__ Tg,
    float* __restrict__ Mg, float* __restrict__ Bg) {
  __shared__ __align__(16) float Ks[64][LD];
  __shared__ __align__(16) float Vs[64][LD];
  __shared__ __align__(16) float As[64][LD];
  __shared__ __align__(16) float Tt[64][LD];
  __shared__ __align__(16) float Pv[64][LD];
  const int cb = blockIdx.x;
  const int c  = cb >> 3, b = cb & 7;
  const int t  = threadIdx.x;

  {
    const int tau = t >> 2, m0 = (t & 3) << 4;
    const float* src = kvqz + (size_t)((c * 64 + tau) * BB + b) * 256;
#pragma unroll
    for (int u = 0; u < 4; ++u) {
      *(float4*)&Ks[tau][m0 + 4 * u] = *(const float4*)&src[m0 + 4 * u];
      *(float4*)&Vs[tau][m0 + 4 * u] = *(const float4*)&src[64 + m0 + 4 * u];
    }
  }
  __syncthreads();

  const int i0 = (t >> 4) << 2;
  const int j0 = (t & 15) << 2;

  {  // A = K K^T
    float acc[4][4];
#pragma unroll
    for (int i = 0; i < 4; ++i)
#pragma unroll
      for (int j = 0; j < 4; ++j) acc[i][j] = 0.f;
    for (int m4 = 0; m4 < 64; m4 += 4) {
      float4 ar[4], br[4];
#pragma unroll
      for (int i = 0; i < 4; ++i) ar[i] = *(const float4*)&Ks[i0 + i][m4];
#pragma unroll
      for (int j = 0; j < 4; ++j) br[j] = *(const float4*)&Ks[j0 + j][m4];
#pragma unroll
      for (int i = 0; i < 4; ++i)
#pragma unroll
        for (int j = 0; j < 4; ++j) acc[i][j] += dot4(ar[i], br[j]);
    }
#pragma unroll
    for (int i = 0; i < 4; ++i)
      *(float4*)&As[i0 + i][j0] =
          make_float4(acc[i][0], acc[i][1], acc[i][2], acc[i][3]);
  }
  __syncthreads();

  if (t < 64) {  // column-parallel forward substitution (transposed storage)
    const int j = t;
    Tt[j][0] = (j == 0) ? 1.f : 0.f;
    for (int i = 1; i < 64; ++i) {
      float acc = 0.f;
      const int nf = i >> 2;
      for (int s4 = 0; s4 < nf; ++s4) {
        float4 av = *(const float4*)&As[i][4 * s4];
        float4 tv = *(const float4*)&Tt[j][4 * s4];
        acc += dot4(av, tv);
      }
      for (int s = 4 * nf; s < i; ++s) acc = fmaf(As[i][s], Tt[j][s], acc);
      Tt[j][i] = (i == j) ? 1.f : -acc;
    }
  }
  __syncthreads();

  {  // P = T K -> As ; Pv = T V
    float accP[4][4], accV[4][4];
#pragma unroll
    for (int i = 0; i < 4; ++i)
#pragma unroll
      for (int j = 0; j < 4; ++j) { accP[i][j] = 0.f; accV[i][j] = 0.f; }
    for (int s = 0; s < 64; ++s) {
      float4 tv = *(const float4*)&Tt[s][i0];
      float4 kv = *(const float4*)&Ks[s][j0];
      float4 vv = *(const float4*)&Vs[s][j0];
      float ta[4] = {tv.x, tv.y, tv.z, tv.w};
      float ka[4] = {kv.x, kv.y, kv.z, kv.w};
      float va[4] = {vv.x, vv.y, vv.z, vv.w};
#pragma unroll
      for (int i = 0; i < 4; ++i)
#pragma unroll
        for (int j = 0; j < 4; ++j) {
          accP[i][j] = fmaf(ta[i], ka[j], accP[i][j]);
          accV[i][j] = fmaf(ta[i], va[j], accV[i][j]);
        }
    }
    __syncthreads();
#pragma unroll
    for (int i = 0; i < 4; ++i) {
      *(float4*)&As[i0 + i][j0] =
          make_float4(accP[i][0], accP[i][1], accP[i][2], accP[i][3]);
      *(float4*)&Pv[i0 + i][j0] =
          make_float4(accV[i][0], accV[i][1], accV[i][2], accV[i][3]);
    }
  }
  __syncthreads();

  {  // M = I - P^T K ; B = Pv^T K  -> global
    float accM[4][4], accB[4][4];
#pragma unroll
    for (int i = 0; i < 4; ++i)
#pragma unroll
      for (int j = 0; j < 4; ++j) { accM[i][j] = 0.f; accB[i][j] = 0.f; }
    for (int s = 0; s < 64; ++s) {
      float4 pv  = *(const float4*)&As[s][i0];
      float4 pvv = *(const float4*)&Pv[s][i0];
      float4 kv  = *(const float4*)&Ks[s][j0];
      float pa[4] = {pv.x, pv.y, pv.z, pv.w};
      float qa[4] = {pvv.x, pvv.y, pvv.z, pvv.w};
      float ka[4] = {kv.x, kv.y, kv.z, kv.w};
#pragma unroll
      for (int i = 0; i < 4; ++i)
#pragma unroll
        for (int j = 0; j < 4; ++j) {
          accM[i][j] = fmaf(pa[i], ka[j], accM[i][j]);
          accB[i][j] = fmaf(qa[i], ka[j], accB[i][j]);
        }
    }
    const size_t base = (size_t)cb * 4096;
#pragma unroll
    for (int i = 0; i < 4; ++i) {
      float m0v = ((i0 + i) == (j0 + 0)) ? 1.f : 0.f;
      float m1v = ((i0 + i) == (j0 + 1)) ? 1.f : 0.f;
      float m2v = ((i0 + i) == (j0 + 2)) ? 1.f : 0.f;
      float m3v = ((i0 + i) == (j0 + 3)) ? 1.f : 0.f;
      *(float4*)&Mg[base + (size_t)(i0 + i) * 64 + j0] =
          make_float4(m0v - accM[i][0], m1v - accM[i][1],
                      m2v - accM[i][2], m3v - accM[i][3]);
      *(float4*)&Bg[base + (size_t)(i0 + i) * 64 + j0] =
          make_float4(accB[i][0], accB[i][1], accB[i][2], accB[i][3]);
    }
    const int fr = t >> 2, fc = (t & 3) << 4;
#pragma unroll
    for (int u = 0; u < 4; ++u)
      *(float4*)&Tg[base + (size_t)fr * 64 + fc + 4 * u] =
          *(const float4*)&Tt[fr][fc + 4 * u];
  }
}

// ---------------------------------------------------------------------------
// Phase 2 (serial over 32 chunks, parallel over 8 batches):
//   Sall[c] = S_{c-1};  S_c = S_{c-1} * M_c + B_c.
// ---------------------------------------------------------------------------
__global__ __launch_bounds__(256) void phase2_kernel(
    const float* __restrict__ Mg, const float* __restrict__ Bg,
    float* __restrict__ Sall) {
  __shared__ __align__(16) float Ss[64][LD];
  __shared__ __align__(16) float Ms[64][LD];
  const int b = blockIdx.x;
  const int t = threadIdx.x;
  const int i0 = (t >> 4) << 2;
  const int j0 = (t & 15) << 2;
  const int fr = t >> 2;
  const int fc = (t & 3) << 4;

  float ns[4][4];
#pragma unroll
  for (int i = 0; i < 4; ++i)
#pragma unroll
    for (int j = 0; j < 4; ++j) ns[i][j] = 0.f;

  float4 pm[4];
  {
    const float* mp = Mg + (size_t)b * 4096 + (size_t)fr * 64 + fc;
#pragma unroll
    for (int u = 0; u < 4; ++u) pm[u] = *(const float4*)&mp[4 * u];
  }

  for (int c = 0; c < NCH; ++c) {
    const size_t cbase = (size_t)(c * BB + b) * 4096;
#pragma unroll
    for (int i = 0; i < 4; ++i) {
      float4 row = make_float4(ns[i][0], ns[i][1], ns[i][2], ns[i][3]);
      *(float4*)&Sall[cbase + (size_t)(i0 + i) * 64 + j0] = row;
      *(float4*)&Ss[i0 + i][j0] = row;
    }
#pragma unroll
    for (int u = 0; u < 4; ++u) *(float4*)&Ms[fr][fc + 4 * u] = pm[u];
    __syncthreads();

    if (c + 1 < NCH) {
      const float* mp = Mg + (size_t)((c + 1) * BB + b) * 4096 + (size_t)fr * 64 + fc;
#pragma unroll
      for (int u = 0; u < 4; ++u) pm[u] = *(const float4*)&mp[4 * u];
    }
    float4 bv[4];
#pragma unroll
    for (int i = 0; i < 4; ++i)
      bv[i] = *(const float4*)&Bg[cbase + (size_t)(i0 + i) * 64 + j0];

    float acc[4][4];
#pragma unroll
    for (int i = 0; i < 4; ++i)
#pragma unroll
      for (int j = 0; j < 4; ++j) acc[i][j] = 0.f;
    for (int m4 = 0; m4 < 64; m4 += 4) {
      float4 sv[4], mv[4];
#pragma unroll
      for (int i = 0; i < 4; ++i) sv[i] = *(const float4*)&Ss[i0 + i][m4];
#pragma unroll
      for (int j2 = 0; j2 < 4; ++j2) mv[j2] = *(const float4*)&Ms[m4 + j2][j0];
      float ma[4][4] = {{mv[0].x, mv[0].y, mv[0].z, mv[0].w},
                        {mv[1].x, mv[1].y, mv[1].z, mv[1].w},
                        {mv[2].x, mv[2].y, mv[2].z, mv[2].w},
                        {mv[3].x, mv[3].y, mv[3].z, mv[3].w}};
#pragma unroll
      for (int i = 0; i < 4; ++i) {
        float sa[4] = {sv[i].x, sv[i].y, sv[i].z, sv[i].w};
#pragma unroll
        for (int j = 0; j < 4; ++j)
          acc[i][j] += sa[0] * ma[0][j] + sa[1] * ma[1][j] +
                       sa[2] * ma[2][j] + sa[3] * ma[3][j];
      }
    }
    float ba[4][4] = {{bv[0].x, bv[0].y, bv[0].z, bv[0].w},
                      {bv[1].x, bv[1].y, bv[1].z, bv[1].w},
                      {bv[2].x, bv[2].y, bv[2].z, bv[2].w},
                      {bv[3].x, bv[3].y, bv[3].z, bv[3].w}};
#pragma unroll
    for (int i = 0; i < 4; ++i)
#pragma unroll
      for (int j = 0; j < 4; ++j) ns[i][j] = acc[i][j] + ba[i][j];
    __syncthreads();
  }
}

// ---------------------------------------------------------------------------
// Phase 3 (parallel over 256 chunk-batch units):
//   Gt = (Q K^T)^T ; W = V - K S0^T ; U = T W ;
//   Y = Q S0^T + tril(G) U ; y = tanh(Y) * sigmoid(Z)  -> ys
// ---------------------------------------------------------------------------
__global__ __launch_bounds__(256) void phase3_kernel(
    const float* __restrict__ kvqz, const float* __restrict__ Tg,
    const float* __restrict__ Sall, float* __restrict__ ys) {
  __shared__ __align__(16) float Ks[64][LD];
  __shared__ __align__(16) float Qs[64][LD];
  __shared__ __align__(16) float S0s[64][LD];
  __shared__ __align__(16) float Tts[64][LD];
  __shared__ __align__(16) float Gts[64][LD];
  __shared__ __align__(16) float Ws[64][LD];
  __shared__ __align__(16) float Us[64][LD];
  const int cb = blockIdx.x;
  const int c  = cb >> 3, b = cb & 7;
  const int t  = threadIdx.x;
  const size_t base = (size_t)cb * 4096;

  {
    const int tau = t >> 2, m0 = (t & 3) << 4;
    const float* src = kvqz + (size_t)((c * 64 + tau) * BB + b) * 256;
#pragma unroll
    for (int u = 0; u < 4; ++u) {
      *(float4*)&Ks[tau][m0 + 4 * u]  = *(const float4*)&src[m0 + 4 * u];
      *(float4*)&Qs[tau][m0 + 4 * u]  = *(const float4*)&src[128 + m0 + 4 * u];
      *(float4*)&S0s[tau][m0 + 4 * u] = *(const float4*)&Sall[base + (size_t)tau * 64 + m0 + 4 * u];
      *(float4*)&Tts[tau][m0 + 4 * u] = *(const float4*)&Tg[base + (size_t)tau * 64 + m0 + 4 * u];
    }
  }
  __syncthreads();

  const int i0 = (t >> 4) << 2;
  const int j0 = (t & 15) << 2;

  {  // Gt[s][tq] = sum_m K[s][m] Q[tq][m]
    float acc[4][4];
#pragma unroll
    for (int i = 0; i < 4; ++i)
#pragma unroll
      for (int j = 0; j < 4; ++j) acc[i][j] = 0.f;
    for (int m4 = 0; m4 < 64; m4 += 4) {
      float4 kr[4], qr[4];
#pragma unroll
      for (int i = 0; i < 4; ++i) kr[i] = *(const float4*)&Ks[i0 + i][m4];
#pragma unroll
      for (int j = 0; j < 4; ++j) qr[j] = *(const float4*)&Qs[j0 + j][m4];
#pragma unroll
      for (int i = 0; i < 4; ++i)
#pragma unroll
        for (int j = 0; j < 4; ++j) acc[i][j] += dot4(kr[i], qr[j]);
    }
#pragma unroll
    for (int i = 0; i < 4; ++i)
      *(float4*)&Gts[i0 + i][j0] =
          make_float4(acc[i][0], acc[i][1], acc[i][2], acc[i][3]);
  }

  {  // W[tau][n] = V[tau][n] - sum_m K[tau][m] S0[n][m]
    float acc[4][4];
#pragma unroll
    for (int i = 0; i < 4; ++i) {
      const float* vrow = kvqz + (size_t)((c * 64 + i0 + i) * BB + b) * 256 + 64;
      float4 vv = *(const float4*)&vrow[j0];
      acc[i][0] = vv.x; acc[i][1] = vv.y; acc[i][2] = vv.z; acc[i][3] = vv.w;
    }
    for (int m4 = 0; m4 < 64; m4 += 4) {
      float4 kr[4], sr[4];
#pragma unroll
      for (int i = 0; i < 4; ++i) kr[i] = *(const float4*)&Ks[i0 + i][m4];
#pragma unroll
      for (int j = 0; j < 4; ++j) sr[j] = *(const float4*)&S0s[j0 + j][m4];
#pragma unroll
      for (int i = 0; i < 4; ++i)
#pragma unroll
        for (int j = 0; j < 4; ++j) acc[i][j] -= dot4(kr[i], sr[j]);
    }
    __syncthreads();
#pragma unroll
    for (int i = 0; i < 4; ++i)
      *(float4*)&Ws[i0 + i][j0] =
          make_float4(acc[i][0], acc[i][1], acc[i][2], acc[i][3]);
  }
  __syncthreads();

  float4 zv[4];
  {  // U[tq][n] = sum_s Tt[s][tq] W[s][n]
#pragma unroll
    for (int i = 0; i < 4; ++i) {
      const float* zrow = kvqz + (size_t)((c * 64 + i0 + i) * BB + b) * 256 + 192;
      zv[i] = *(const float4*)&zrow[j0];
    }
    float acc[4][4];
#pragma unroll
    for (int i = 0; i < 4; ++i)
#pragma unroll
      for (int j = 0; j < 4; ++j) acc[i][j] = 0.f;
    for (int s = 0; s < 64; ++s) {
      float4 tv = *(const float4*)&Tts[s][i0];
      float4 wv = *(const float4*)&Ws[s][j0];
      float ta[4] = {tv.x, tv.y, tv.z, tv.w};
      float wa[4] = {wv.x, wv.y, wv.z, wv.w};
#pragma unroll
      for (int i = 0; i < 4; ++i)
#pragma unroll
        for (int j = 0; j < 4; ++j) acc[i][j] = fmaf(ta[i], wa[j], acc[i][j]);
    }
    __syncthreads();
#pragma unroll
    for (int i = 0; i < 4; ++i)
      *(float4*)&Us[i0 + i][j0] =
          make_float4(acc[i][0], acc[i][1], acc[i][2], acc[i][3]);
  }
  __syncthreads();

  {  // Y = Q S0^T + tril(G) U ; out
    float acc[4][4];
#pragma unroll
    for (int i = 0; i < 4; ++i)
#pragma unroll
      for (int j = 0; j < 4; ++j) acc[i][j] = 0.f;
    for (int m4 = 0; m4 < 64; m4 += 4) {
      float4 qr[4], sr[4];
#pragma unroll
      for (int i = 0; i < 4; ++i) qr[i] = *(const float4*)&Qs[i0 + i][m4];
#pragma unroll
      for (int j = 0; j < 4; ++j) sr[j] = *(const float4*)&S0s[j0 + j][m4];
#pragma unroll
      for (int i = 0; i < 4; ++i)
#pragma unroll
        for (int j = 0; j < 4; ++j) acc[i][j] += dot4(qr[i], sr[j]);
    }
    for (int s = 0; s < 64; ++s) {
      float4 gv = *(const float4*)&Gts[s][i0];
      float4 uv = *(const float4*)&Us[s][j0];
      float ga[4] = {gv.x, gv.y, gv.z, gv.w};
      float ua[4] = {uv.x, uv.y, uv.z, uv.w};
#pragma unroll
      for (int i = 0; i < 4; ++i) {
        float gi = (s <= i0 + i) ? ga[i] : 0.f;
#pragma unroll
        for (int j = 0; j < 4; ++j) acc[i][j] = fmaf(gi, ua[j], acc[i][j]);
      }
    }
#pragma unroll
    for (int i = 0; i < 4; ++i) {
      float za[4] = {zv[i].x, zv[i].y, zv[i].z, zv[i].w};
      float4 o;
      float* op = &o.x;
#pragma unroll
      for (int j = 0; j < 4; ++j) {
        float e2 = __expf(2.f * acc[i][j]);
        float th = 1.f - 2.f / (e2 + 1.f);
        float sg = 1.f / (1.f + __expf(-za[j]));
        op[j] = th * sg;
      }
      *(float4*)&ys[(size_t)((c * 64 + i0 + i) * BB + b) * 64 + j0] = o;
    }
  }
}

// ---------------------------------------------------------------------------
extern "C" void kernel_launch(void* const* d_in, const int* in_sizes, int n_in,
                              void* d_out, int out_size, void* d_ws, size_t ws_size,
                              hipStream_t stream) {
  const float* x    = (const float*)d_in[0];
  const float* Win  = (const float*)d_in[1];
  const float* Wk   = (const float*)d_in[2];
  const float* Wv   = (const float*)d_in[3];
  const float* Wq   = (const float*)d_in[4];
  const float* Wz   = (const float*)d_in[5];
  const float* Wout = (const float*)d_in[6];
  float* out = (float*)d_out;

  char* ws = (char*)d_ws;
  float* Wf   = (float*)(ws);                  // 1 MB
  float* kvqz = (float*)(ws + (1u  << 20));    // 16 MB
  float* ys   = (float*)(ws + (17u << 20));    // 4 MB
  float* Tg   = (float*)(ws + (21u << 20));    // 4 MB
  float* Mg   = (float*)(ws + (25u << 20));    // 4 MB
  float* Bg   = (float*)(ws + (29u << 20));    // 4 MB
  float* Sall = (float*)(ws + (33u << 20));    // 4 MB  (37 MB total)
  // Pg (16 MB, split-K partials) aliases Tg..Sall: consumed by fuse_reduce
  // before phase1 writes Tg/Mg/Bg.
  float* Pg   = (float*)(ws + (21u << 20));

  fuse_gemm_kernel<<<dim3(DIM_ / 128, 2, KSPL), 256, 0, stream>>>(Wk, Wv, Wq, Wz, Win, Pg);
  fuse_reduce_kernel<<<(256 * DIM_ / 4) / 256, 256, 0, stream>>>(Pg, Wf);
  gemm_abt<<<dim3(256 / 128, MR_ / 128), 256, 0, stream>>>(x, Wf, kvqz, MR_, 256, DIM_);
  norm_k_kernel<<<MR_ / 4, 256, 0, stream>>>(kvqz);
  phase1_kernel<<<NCH * BB, 256, 0, stream>>>(kvqz, Tg, Mg, Bg);
  phase2_kernel<<<BB, 256, 0, stream>>>(Mg, Bg, Sall);
  phase3_kernel<<<NCH * BB, 256, 0, stream>>>(kvqz, Tg, Sall, ys);
  gemm_abt<<<dim3(DIM_ / 128, MR_ / 128), 256, 0, stream>>>(ys, Wout, out, MR_, DIM_, NS_);
}

// Round 4
// 386.571 us; speedup vs baseline: 5.4985x; 1.3035x over previous
//
#include <hip/hip_runtime.h>
#include <math.h>

#define TT   2048
#define BB   8
#define DIM_ 1024
#define DI_  2048
#define NS_  64
#define MR_  (TT * BB)   // 16384 rows (t-major, b-minor)
#define NCH  32          // chunks of 64 steps
#define LD   68          // padded LDS leading dim (16B-aligned rows)
#define KSPL 16          // split-K factor for fuse GEMM
#define KCH  (DI_ / KSPL)

typedef _Float16 half8 __attribute__((ext_vector_type(8)));
typedef float floatx4 __attribute__((ext_vector_type(4)));

__device__ __forceinline__ float dot4(float4 a, float4 b) {
  return a.x * b.x + a.y * b.y + a.z * b.z + a.w * b.w;
}

// ---------------------------------------------------------------------------
// f16 MFMA GEMM: C[M,N] = A[M,K] * B[N,K]^T. A,B fp32 in memory, converted to
// f16 during LDS staging. 128x128 tile, BK=32, 4 waves x (4x4) 16x16x32 MFMA.
// M,N multiples of 128; K multiple of 32.
// ---------------------------------------------------------------------------
__global__ __launch_bounds__(256) void gemm16_abt(
    const float* __restrict__ A, const float* __restrict__ B,
    float* __restrict__ C, int M, int N, int K) {
  __shared__ _Float16 Ah[128 * 32];   // 8 KB, row-major [128][32]
  __shared__ _Float16 Bh[128 * 32];   // 8 KB
  const int tid  = threadIdx.x;
  const int m0   = blockIdx.y * 128;
  const int n0   = blockIdx.x * 128;
  const int wave = tid >> 6, lane = tid & 63;
  const int wm   = (wave >> 1) * 64;       // wave row base
  const int wn   = (wave & 1) * 64;        // wave col base
  const int quad = lane >> 4, l16 = lane & 15;
  // staging: thread handles rows {srow, 64+srow}, k-chunk skq..skq+8
  const int srow = tid >> 2;               // 0..63
  const int skq  = (tid & 3) * 8;          // 0,8,16,24 (f16 elems)

  floatx4 acc[4][4];
#pragma unroll
  for (int i = 0; i < 4; ++i)
#pragma unroll
    for (int j = 0; j < 4; ++j) acc[i][j] = (floatx4)0.f;

  for (int k0 = 0; k0 < K; k0 += 32) {
    // global loads (fp32), 8 floats per (tensor, pass)
    float4 a00 = *(const float4*)&A[(size_t)(m0 + srow)      * K + k0 + skq];
    float4 a01 = *(const float4*)&A[(size_t)(m0 + srow)      * K + k0 + skq + 4];
    float4 a10 = *(const float4*)&A[(size_t)(m0 + 64 + srow) * K + k0 + skq];
    float4 a11 = *(const float4*)&A[(size_t)(m0 + 64 + srow) * K + k0 + skq + 4];
    float4 b00 = *(const float4*)&B[(size_t)(n0 + srow)      * K + k0 + skq];
    float4 b01 = *(const float4*)&B[(size_t)(n0 + srow)      * K + k0 + skq + 4];
    float4 b10 = *(const float4*)&B[(size_t)(n0 + 64 + srow) * K + k0 + skq];
    float4 b11 = *(const float4*)&B[(size_t)(n0 + 64 + srow) * K + k0 + skq + 4];
    __syncthreads();  // previous tile fully consumed
    {
      half8 ha0 = {(_Float16)a00.x, (_Float16)a00.y, (_Float16)a00.z, (_Float16)a00.w,
                   (_Float16)a01.x, (_Float16)a01.y, (_Float16)a01.z, (_Float16)a01.w};
      half8 ha1 = {(_Float16)a10.x, (_Float16)a10.y, (_Float16)a10.z, (_Float16)a10.w,
                   (_Float16)a11.x, (_Float16)a11.y, (_Float16)a11.z, (_Float16)a11.w};
      half8 hb0 = {(_Float16)b00.x, (_Float16)b00.y, (_Float16)b00.z, (_Float16)b00.w,
                   (_Float16)b01.x, (_Float16)b01.y, (_Float16)b01.z, (_Float16)b01.w};
      half8 hb1 = {(_Float16)b10.x, (_Float16)b10.y, (_Float16)b10.z, (_Float16)b10.w,
                   (_Float16)b11.x, (_Float16)b11.y, (_Float16)b11.z, (_Float16)b11.w};
      *(half8*)&Ah[(srow)      * 32 + skq] = ha0;
      *(half8*)&Ah[(64 + srow) * 32 + skq] = ha1;
      *(half8*)&Bh[(srow)      * 32 + skq] = hb0;
      *(half8*)&Bh[(64 + srow) * 32 + skq] = hb1;
    }
    __syncthreads();

    half8 af[4], bf[4];
#pragma unroll
    for (int mt = 0; mt < 4; ++mt)
      af[mt] = *(const half8*)&Ah[(wm + mt * 16 + l16) * 32 + quad * 8];
#pragma unroll
    for (int nt = 0; nt < 4; ++nt)
      bf[nt] = *(const half8*)&Bh[(wn + nt * 16 + l16) * 32 + quad * 8];
#pragma unroll
    for (int mt = 0; mt < 4; ++mt)
#pragma unroll
      for (int nt = 0; nt < 4; ++nt)
        acc[mt][nt] = __builtin_amdgcn_mfma_f32_16x16x32_f16(
            af[mt], bf[nt], acc[mt][nt], 0, 0, 0);
  }

  // epilogue: C/D layout row = quad*4 + i, col = l16
#pragma unroll
  for (int mt = 0; mt < 4; ++mt) {
#pragma unroll
    for (int i = 0; i < 4; ++i) {
      const size_t r = (size_t)(m0 + wm + mt * 16 + quad * 4 + i) * N;
#pragma unroll
      for (int nt = 0; nt < 4; ++nt)
        C[r + n0 + wn + nt * 16 + l16] = acc[mt][nt][i];
    }
  }
}

// ---------------------------------------------------------------------------
// fuse GEMM (split-K): Pg[ks] partial of Wf[256][1024] = Wg[256][2048]*Win[2048][1024]
// ---------------------------------------------------------------------------
__global__ __launch_bounds__(256) void fuse_gemm_kernel(
    const float* __restrict__ Wk, const float* __restrict__ Wv,
    const float* __restrict__ Wq, const float* __restrict__ Wz,
    const float* __restrict__ Win, float* __restrict__ Pg) {
  __shared__ __align__(16) float As[16][132];
  __shared__ __align__(16) float Bs[16][132];
  const int tid = threadIdx.x;
  const int n0  = blockIdx.x * 128;
  const int m0  = blockIdx.y * 128;
  const int kb  = blockIdx.z * KCH;
  const int lrow = tid >> 2;
  const int lk4  = (tid & 3) << 2;
  const int tm   = (tid & 15) << 2;
  const int tn   = (tid >> 4) << 2;
  const float* Wg[4] = {Wk, Wv, Wq, Wz};
  const int ra = m0 + lrow, rb = m0 + 64 + lrow;
  const float* arow0 = Wg[ra >> 6] + (size_t)(ra & 63) * DI_;
  const float* arow1 = Wg[rb >> 6] + (size_t)(rb & 63) * DI_;
  const int brow = tid >> 5;
  const int bcol = (tid & 31) << 2;

  float acc[8][8];
#pragma unroll
  for (int i = 0; i < 8; ++i)
#pragma unroll
    for (int j = 0; j < 8; ++j) acc[i][j] = 0.f;

  for (int k0 = 0; k0 < KCH; k0 += 16) {
    float4 av0 = *(const float4*)&arow0[kb + k0 + lk4];
    float4 av1 = *(const float4*)&arow1[kb + k0 + lk4];
    float4 bv0 = *(const float4*)&Win[(size_t)(kb + k0 + brow)     * DIM_ + n0 + bcol];
    float4 bv1 = *(const float4*)&Win[(size_t)(kb + k0 + 8 + brow) * DIM_ + n0 + bcol];
    __syncthreads();
    As[lk4 + 0][lrow] = av0.x; As[lk4 + 1][lrow] = av0.y;
    As[lk4 + 2][lrow] = av0.z; As[lk4 + 3][lrow] = av0.w;
    As[lk4 + 0][64 + lrow] = av1.x; As[lk4 + 1][64 + lrow] = av1.y;
    As[lk4 + 2][64 + lrow] = av1.z; As[lk4 + 3][64 + lrow] = av1.w;
    *(float4*)&Bs[brow][bcol]     = bv0;
    *(float4*)&Bs[brow + 8][bcol] = bv1;
    __syncthreads();
#pragma unroll
    for (int kk = 0; kk < 16; ++kk) {
      float4 a0 = *(const float4*)&As[kk][tm];
      float4 a1 = *(const float4*)&As[kk][tm + 64];
      float4 b0 = *(const float4*)&Bs[kk][tn];
      float4 b1 = *(const float4*)&Bs[kk][tn + 64];
      float ar[8] = {a0.x, a0.y, a0.z, a0.w, a1.x, a1.y, a1.z, a1.w};
      float br[8] = {b0.x, b0.y, b0.z, b0.w, b1.x, b1.y, b1.z, b1.w};
#pragma unroll
      for (int i = 0; i < 8; ++i)
#pragma unroll
        for (int j = 0; j < 8; ++j)
          acc[i][j] = fmaf(ar[i], br[j], acc[i][j]);
    }
  }
  float* P = Pg + (size_t)blockIdx.z * (256 * DIM_);
#pragma unroll
  for (int i = 0; i < 8; ++i) {
    int r = m0 + tm + (i & 3) + ((i >> 2) << 6);
    float4 c0 = make_float4(acc[i][0], acc[i][1], acc[i][2], acc[i][3]);
    float4 c1 = make_float4(acc[i][4], acc[i][5], acc[i][6], acc[i][7]);
    *(float4*)&P[(size_t)r * DIM_ + n0 + tn]      = c0;
    *(float4*)&P[(size_t)r * DIM_ + n0 + tn + 64] = c1;
  }
}

// Wf[i] = sum_ks Pg[ks][i]
__global__ __launch_bounds__(256) void fuse_reduce_kernel(
    const float* __restrict__ Pg, float* __restrict__ Wf) {
  const size_t i = ((size_t)blockIdx.x * 256 + threadIdx.x) << 2;
  float4 s = *(const float4*)&Pg[i];
#pragma unroll
  for (int ks = 1; ks < KSPL; ++ks) {
    float4 p = *(const float4*)&Pg[(size_t)ks * (256 * DIM_) + i];
    s.x += p.x; s.y += p.y; s.z += p.z; s.w += p.w;
  }
  *(float4*)&Wf[i] = s;
}

// ---------------------------------------------------------------------------
// Unit-normalize each k row (first 64 cols of kvqz).
// ---------------------------------------------------------------------------
__global__ __launch_bounds__(256) void norm_k_kernel(float* __restrict__ kvqz) {
  const int wid  = (blockIdx.x * 256 + threadIdx.x) >> 6;
  const int lane = threadIdx.x & 63;
  float x = kvqz[(size_t)wid * 256 + lane];
  float s = x * x;
  s += __shfl_xor(s, 1);  s += __shfl_xor(s, 2);  s += __shfl_xor(s, 4);
  s += __shfl_xor(s, 8);  s += __shfl_xor(s, 16); s += __shfl_xor(s, 32);
  kvqz[(size_t)wid * 256 + lane] = x / (sqrtf(s) + 1e-6f);
}

// ---------------------------------------------------------------------------
// Phase 1: per chunk-batch:  A = K K^T ; Tt = inv(I+stril(A)) (transposed);
// P = T K ; Pv = T V ; M = I - P^T K ; B = Pv^T K.  Store Tt, M, B.
// ---------------------------------------------------------------------------
__global__ __launch_bounds__(256) void phase1_kernel(
    const float* __restrict__ kvqz, float* __restrict__ Tg,
    float* __restrict__ Mg, float* __restrict__ Bg) {
  __shared__ __align__(16) float Ks[64][LD];
  __shared__ __align__(16) float Vs[64][LD];
  __shared__ __align__(16) float As[64][LD];
  __shared__ __align__(16) float Tt[64][LD];
  __shared__ __align__(16) float Pv[64][LD];
  const int cb = blockIdx.x;
  const int c  = cb >> 3, b = cb & 7;
  const int t  = threadIdx.x;

  {
    const int tau = t >> 2, m0 = (t & 3) << 4;
    const float* src = kvqz + (size_t)((c * 64 + tau) * BB + b) * 256;
#pragma unroll
    for (int u = 0; u < 4; ++u) {
      *(float4*)&Ks[tau][m0 + 4 * u] = *(const float4*)&src[m0 + 4 * u];
      *(float4*)&Vs[tau][m0 + 4 * u] = *(const float4*)&src[64 + m0 + 4 * u];
    }
  }
  __syncthreads();

  const int i0 = (t >> 4) << 2;
  const int j0 = (t & 15) << 2;

  {  // A = K K^T
    float acc[4][4];
#pragma unroll
    for (int i = 0; i < 4; ++i)
#pragma unroll
      for (int j = 0; j < 4; ++j) acc[i][j] = 0.f;
    for (int m4 = 0; m4 < 64; m4 += 4) {
      float4 ar[4], br[4];
#pragma unroll
      for (int i = 0; i < 4; ++i) ar[i] = *(const float4*)&Ks[i0 + i][m4];
#pragma unroll
      for (int j = 0; j < 4; ++j) br[j] = *(const float4*)&Ks[j0 + j][m4];
#pragma unroll
      for (int i = 0; i < 4; ++i)
#pragma unroll
        for (int j = 0; j < 4; ++j) acc[i][j] += dot4(ar[i], br[j]);
    }
#pragma unroll
    for (int i = 0; i < 4; ++i)
      *(float4*)&As[i0 + i][j0] =
          make_float4(acc[i][0], acc[i][1], acc[i][2], acc[i][3]);
  }
  __syncthreads();

  if (t < 64) {  // column-parallel forward substitution (transposed storage)
    const int j = t;
    Tt[j][0] = (j == 0) ? 1.f : 0.f;
    for (int i = 1; i < 64; ++i) {
      float acc = 0.f;
      const int nf = i >> 2;
      for (int s4 = 0; s4 < nf; ++s4) {
        float4 av = *(const float4*)&As[i][4 * s4];
        float4 tv = *(const float4*)&Tt[j][4 * s4];
        acc += dot4(av, tv);
      }
      for (int s = 4 * nf; s < i; ++s) acc = fmaf(As[i][s], Tt[j][s], acc);
      Tt[j][i] = (i == j) ? 1.f : -acc;
    }
  }
  __syncthreads();

  {  // P = T K -> As ; Pv = T V
    float accP[4][4], accV[4][4];
#pragma unroll
    for (int i = 0; i < 4; ++i)
#pragma unroll
      for (int j = 0; j < 4; ++j) { accP[i][j] = 0.f; accV[i][j] = 0.f; }
    for (int s = 0; s < 64; ++s) {
      float4 tv = *(const float4*)&Tt[s][i0];
      float4 kv = *(const float4*)&Ks[s][j0];
      float4 vv = *(const float4*)&Vs[s][j0];
      float ta[4] = {tv.x, tv.y, tv.z, tv.w};
      float ka[4] = {kv.x, kv.y, kv.z, kv.w};
      float va[4] = {vv.x, vv.y, vv.z, vv.w};
#pragma unroll
      for (int i = 0; i < 4; ++i)
#pragma unroll
        for (int j = 0; j < 4; ++j) {
          accP[i][j] = fmaf(ta[i], ka[j], accP[i][j]);
          accV[i][j] = fmaf(ta[i], va[j], accV[i][j]);
        }
    }
    __syncthreads();
#pragma unroll
    for (int i = 0; i < 4; ++i) {
      *(float4*)&As[i0 + i][j0] =
          make_float4(accP[i][0], accP[i][1], accP[i][2], accP[i][3]);
      *(float4*)&Pv[i0 + i][j0] =
          make_float4(accV[i][0], accV[i][1], accV[i][2], accV[i][3]);
    }
  }
  __syncthreads();

  {  // M = I - P^T K ; B = Pv^T K  -> global
    float accM[4][4], accB[4][4];
#pragma unroll
    for (int i = 0; i < 4; ++i)
#pragma unroll
      for (int j = 0; j < 4; ++j) { accM[i][j] = 0.f; accB[i][j] = 0.f; }
    for (int s = 0; s < 64; ++s) {
      float4 pv  = *(const float4*)&As[s][i0];
      float4 pvv = *(const float4*)&Pv[s][i0];
      float4 kv  = *(const float4*)&Ks[s][j0];
      float pa[4] = {pv.x, pv.y, pv.z, pv.w};
      float qa[4] = {pvv.x, pvv.y, pvv.z, pvv.w};
      float ka[4] = {kv.x, kv.y, kv.z, kv.w};
#pragma unroll
      for (int i = 0; i < 4; ++i)
#pragma unroll
        for (int j = 0; j < 4; ++j) {
          accM[i][j] = fmaf(pa[i], ka[j], accM[i][j]);
          accB[i][j] = fmaf(qa[i], ka[j], accB[i][j]);
        }
    }
    const size_t base = (size_t)cb * 4096;
#pragma unroll
    for (int i = 0; i < 4; ++i) {
      float m0v = ((i0 + i) == (j0 + 0)) ? 1.f : 0.f;
      float m1v = ((i0 + i) == (j0 + 1)) ? 1.f : 0.f;
      float m2v = ((i0 + i) == (j0 + 2)) ? 1.f : 0.f;
      float m3v = ((i0 + i) == (j0 + 3)) ? 1.f : 0.f;
      *(float4*)&Mg[base + (size_t)(i0 + i) * 64 + j0] =
          make_float4(m0v - accM[i][0], m1v - accM[i][1],
                      m2v - accM[i][2], m3v - accM[i][3]);
      *(float4*)&Bg[base + (size_t)(i0 + i) * 64 + j0] =
          make_float4(accB[i][0], accB[i][1], accB[i][2], accB[i][3]);
    }
    const int fr = t >> 2, fc = (t & 3) << 4;
#pragma unroll
    for (int u = 0; u < 4; ++u)
      *(float4*)&Tg[base + (size_t)fr * 64 + fc + 4 * u] =
          *(const float4*)&Tt[fr][fc + 4 * u];
  }
}

// ---------------------------------------------------------------------------
// Phase 2 (serial over 32 chunks, parallel over 8 batches):
//   Sall[c] = S_{c-1};  S_c = S_{c-1} * M_c + B_c.
// ---------------------------------------------------------------------------
__global__ __launch_bounds__(256) void phase2_kernel(
    const float* __restrict__ Mg, const float* __restrict__ Bg,
    float* __restrict__ Sall) {
  __shared__ __align__(16) float Ss[64][LD];
  __shared__ __align__(16) float Ms[64][LD];
  const int b = blockIdx.x;
  const int t = threadIdx.x;
  const int i0 = (t >> 4) << 2;
  const int j0 = (t & 15) << 2;
  const int fr = t >> 2;
  const int fc = (t & 3) << 4;

  float ns[4][4];
#pragma unroll
  for (int i = 0; i < 4; ++i)
#pragma unroll
    for (int j = 0; j < 4; ++j) ns[i][j] = 0.f;

  float4 pm[4];
  {
    const float* mp = Mg + (size_t)b * 4096 + (size_t)fr * 64 + fc;
#pragma unroll
    for (int u = 0; u < 4; ++u) pm[u] = *(const float4*)&mp[4 * u];
  }

  for (int c = 0; c < NCH; ++c) {
    const size_t cbase = (size_t)(c * BB + b) * 4096;
#pragma unroll
    for (int i = 0; i < 4; ++i) {
      float4 row = make_float4(ns[i][0], ns[i][1], ns[i][2], ns[i][3]);
      *(float4*)&Sall[cbase + (size_t)(i0 + i) * 64 + j0] = row;
      *(float4*)&Ss[i0 + i][j0] = row;
    }
#pragma unroll
    for (int u = 0; u < 4; ++u) *(float4*)&Ms[fr][fc + 4 * u] = pm[u];
    __syncthreads();

    if (c + 1 < NCH) {
      const float* mp = Mg + (size_t)((c + 1) * BB + b) * 4096 + (size_t)fr * 64 + fc;
#pragma unroll
      for (int u = 0; u < 4; ++u) pm[u] = *(const float4*)&mp[4 * u];
    }
    float4 bv[4];
#pragma unroll
    for (int i = 0; i < 4; ++i)
      bv[i] = *(const float4*)&Bg[cbase + (size_t)(i0 + i) * 64 + j0];

    float acc[4][4];
#pragma unroll
    for (int i = 0; i < 4; ++i)
#pragma unroll
      for (int j = 0; j < 4; ++j) acc[i][j] = 0.f;
    for (int m4 = 0; m4 < 64; m4 += 4) {
      float4 sv[4], mv[4];
#pragma unroll
      for (int i = 0; i < 4; ++i) sv[i] = *(const float4*)&Ss[i0 + i][m4];
#pragma unroll
      for (int j2 = 0; j2 < 4; ++j2) mv[j2] = *(const float4*)&Ms[m4 + j2][j0];
      float ma[4][4] = {{mv[0].x, mv[0].y, mv[0].z, mv[0].w},
                        {mv[1].x, mv[1].y, mv[1].z, mv[1].w},
                        {mv[2].x, mv[2].y, mv[2].z, mv[2].w},
                        {mv[3].x, mv[3].y, mv[3].z, mv[3].w}};
#pragma unroll
      for (int i = 0; i < 4; ++i) {
        float sa[4] = {sv[i].x, sv[i].y, sv[i].z, sv[i].w};
#pragma unroll
        for (int j = 0; j < 4; ++j)
          acc[i][j] += sa[0] * ma[0][j] + sa[1] * ma[1][j] +
                       sa[2] * ma[2][j] + sa[3] * ma[3][j];
      }
    }
    float ba[4][4] = {{bv[0].x, bv[0].y, bv[0].z, bv[0].w},
                      {bv[1].x, bv[1].y, bv[1].z, bv[1].w},
                      {bv[2].x, bv[2].y, bv[2].z, bv[2].w},
                      {bv[3].x, bv[3].y, bv[3].z, bv[3].w}};
#pragma unroll
    for (int i = 0; i < 4; ++i)
#pragma unroll
      for (int j = 0; j < 4; ++j) ns[i][j] = acc[i][j] + ba[i][j];
    __syncthreads();
  }
}

// ---------------------------------------------------------------------------
// Phase 3: Gt = (Q K^T)^T ; W = V - K S0^T ; U = T W ;
//   Y = Q S0^T + tril(G) U ; y = tanh(Y) * sigmoid(Z)  -> ys
// ---------------------------------------------------------------------------
__global__ __launch_bounds__(256) void phase3_kernel(
    const float* __restrict__ kvqz, const float* __restrict__ Tg,
    const float* __restrict__ Sall, float* __restrict__ ys) {
  __shared__ __align__(16) float Ks[64][LD];
  __shared__ __align__(16) float Qs[64][LD];
  __shared__ __align__(16) float S0s[64][LD];
  __shared__ __align__(16) float Tts[64][LD];
  __shared__ __align__(16) float Gts[64][LD];
  __shared__ __align__(16) float Ws[64][LD];
  __shared__ __align__(16) float Us[64][LD];
  const int cb = blockIdx.x;
  const int c  = cb >> 3, b = cb & 7;
  const int t  = threadIdx.x;
  const size_t base = (size_t)cb * 4096;

  {
    const int tau = t >> 2, m0 = (t & 3) << 4;
    const float* src = kvqz + (size_t)((c * 64 + tau) * BB + b) * 256;
#pragma unroll
    for (int u = 0; u < 4; ++u) {
      *(float4*)&Ks[tau][m0 + 4 * u]  = *(const float4*)&src[m0 + 4 * u];
      *(float4*)&Qs[tau][m0 + 4 * u]  = *(const float4*)&src[128 + m0 + 4 * u];
      *(float4*)&S0s[tau][m0 + 4 * u] = *(const float4*)&Sall[base + (size_t)tau * 64 + m0 + 4 * u];
      *(float4*)&Tts[tau][m0 + 4 * u] = *(const float4*)&Tg[base + (size_t)tau * 64 + m0 + 4 * u];
    }
  }
  __syncthreads();

  const int i0 = (t >> 4) << 2;
  const int j0 = (t & 15) << 2;

  {  // Gt[s][tq] = sum_m K[s][m] Q[tq][m]
    float acc[4][4];
#pragma unroll
    for (int i = 0; i < 4; ++i)
#pragma unroll
      for (int j = 0; j < 4; ++j) acc[i][j] = 0.f;
    for (int m4 = 0; m4 < 64; m4 += 4) {
      float4 kr[4], qr[4];
#pragma unroll
      for (int i = 0; i < 4; ++i) kr[i] = *(const float4*)&Ks[i0 + i][m4];
#pragma unroll
      for (int j = 0; j < 4; ++j) qr[j] = *(const float4*)&Qs[j0 + j][m4];
#pragma unroll
      for (int i = 0; i < 4; ++i)
#pragma unroll
        for (int j = 0; j < 4; ++j) acc[i][j] += dot4(kr[i], qr[j]);
    }
#pragma unroll
    for (int i = 0; i < 4; ++i)
      *(float4*)&Gts[i0 + i][j0] =
          make_float4(acc[i][0], acc[i][1], acc[i][2], acc[i][3]);
  }

  {  // W[tau][n] = V[tau][n] - sum_m K[tau][m] S0[n][m]
    float acc[4][4];
#pragma unroll
    for (int i = 0; i < 4; ++i) {
      const float* vrow = kvqz + (size_t)((c * 64 + i0 + i) * BB + b) * 256 + 64;
      float4 vv = *(const float4*)&vrow[j0];
      acc[i][0] = vv.x; acc[i][1] = vv.y; acc[i][2] = vv.z; acc[i][3] = vv.w;
    }
    for (int m4 = 0; m4 < 64; m4 += 4) {
      float4 kr[4], sr[4];
#pragma unroll
      for (int i = 0; i < 4; ++i) kr[i] = *(const float4*)&Ks[i0 + i][m4];
#pragma unroll
      for (int j = 0; j < 4; ++j) sr[j] = *(const float4*)&S0s[j0 + j][m4];
#pragma unroll
      for (int i = 0; i < 4; ++i)
#pragma unroll
        for (int j = 0; j < 4; ++j) acc[i][j] -= dot4(kr[i], sr[j]);
    }
    __syncthreads();
#pragma unroll
    for (int i = 0; i < 4; ++i)
      *(float4*)&Ws[i0 + i][j0] =
          make_float4(acc[i][0], acc[i][1], acc[i][2], acc[i][3]);
  }
  __syncthreads();

  float4 zv[4];
  {  // U[tq][n] = sum_s Tt[s][tq] W[s][n]
#pragma unroll
    for (int i = 0; i < 4; ++i) {
      const float* zrow = kvqz + (size_t)((c * 64 + i0 + i) * BB + b) * 256 + 192;
      zv[i] = *(const float4*)&zrow[j0];
    }
    float acc[4][4];
#pragma unroll
    for (int i = 0; i < 4; ++i)
#pragma unroll
      for (int j = 0; j < 4; ++j) acc[i][j] = 0.f;
    for (int s = 0; s < 64; ++s) {
      float4 tv = *(const float4*)&Tts[s][i0];
      float4 wv = *(const float4*)&Ws[s][j0];
      float ta[4] = {tv.x, tv.y, tv.z, tv.w};
      float wa[4] = {wv.x, wv.y, wv.z, wv.w};
#pragma unroll
      for (int i = 0; i < 4; ++i)
#pragma unroll
        for (int j = 0; j < 4; ++j) acc[i][j] = fmaf(ta[i], wa[j], acc[i][j]);
    }
    __syncthreads();
#pragma unroll
    for (int i = 0; i < 4; ++i)
      *(float4*)&Us[i0 + i][j0] =
          make_float4(acc[i][0], acc[i][1], acc[i][2], acc[i][3]);
  }
  __syncthreads();

  {  // Y = Q S0^T + tril(G) U ; out
    float acc[4][4];
#pragma unroll
    for (int i = 0; i < 4; ++i)
#pragma unroll
      for (int j = 0; j < 4; ++j) acc[i][j] = 0.f;
    for (int m4 = 0; m4 < 64; m4 += 4) {
      float4 qr[4], sr[4];
#pragma unroll
      for (int i = 0; i < 4; ++i) qr[i] = *(const float4*)&Qs[i0 + i][m4];
#pragma unroll
      for (int j = 0; j < 4; ++j) sr[j] = *(const float4*)&S0s[j0 + j][m4];
#pragma unroll
      for (int i = 0; i < 4; ++i)
#pragma unroll
        for (int j = 0; j < 4; ++j) acc[i][j] += dot4(qr[i], sr[j]);
    }
    for (int s = 0; s < 64; ++s) {
      float4 gv = *(const float4*)&Gts[s][i0];
      float4 uv = *(const float4*)&Us[s][j0];
      float ga[4] = {gv.x, gv.y, gv.z, gv.w};
      float ua[4] = {uv.x, uv.y, uv.z, uv.w};
#pragma unroll
      for (int i = 0; i < 4; ++i) {
        float gi = (s <= i0 + i) ? ga[i] : 0.f;
#pragma unroll
        for (int j = 0; j < 4; ++j) acc[i][j] = fmaf(gi, ua[j], acc[i][j]);
      }
    }
#pragma unroll
    for (int i = 0; i < 4; ++i) {
      float za[4] = {zv[i].x, zv[i].y, zv[i].z, zv[i].w};
      float4 o;
      float* op = &o.x;
#pragma unroll
      for (int j = 0; j < 4; ++j) {
        float e2 = __expf(2.f * acc[i][j]);
        float th = 1.f - 2.f / (e2 + 1.f);
        float sg = 1.f / (1.f + __expf(-za[j]));
        op[j] = th * sg;
      }
      *(float4*)&ys[(size_t)((c * 64 + i0 + i) * BB + b) * 64 + j0] = o;
    }
  }
}

// ---------------------------------------------------------------------------
extern "C" void kernel_launch(void* const* d_in, const int* in_sizes, int n_in,
                              void* d_out, int out_size, void* d_ws, size_t ws_size,
                              hipStream_t stream) {
  const float* x    = (const float*)d_in[0];
  const float* Win  = (const float*)d_in[1];
  const float* Wk   = (const float*)d_in[2];
  const float* Wv   = (const float*)d_in[3];
  const float* Wq   = (const float*)d_in[4];
  const float* Wz   = (const float*)d_in[5];
  const float* Wout = (const float*)d_in[6];
  float* out = (float*)d_out;

  char* ws = (char*)d_ws;
  float* Wf   = (float*)(ws);                  // 1 MB
  float* kvqz = (float*)(ws + (1u  << 20));    // 16 MB
  float* ys   = (float*)(ws + (17u << 20));    // 4 MB
  float* Tg   = (float*)(ws + (21u << 20));    // 4 MB
  float* Mg   = (float*)(ws + (25u << 20));    // 4 MB
  float* Bg   = (float*)(ws + (29u << 20));    // 4 MB
  float* Sall = (float*)(ws + (33u << 20));    // 4 MB  (37 MB total)
  // Pg (16 MB) aliases Tg..Sall: consumed by fuse_reduce before phase1 writes.
  float* Pg   = (float*)(ws + (21u << 20));

  fuse_gemm_kernel<<<dim3(DIM_ / 128, 2, KSPL), 256, 0, stream>>>(Wk, Wv, Wq, Wz, Win, Pg);
  fuse_reduce_kernel<<<(256 * DIM_ / 4) / 256, 256, 0, stream>>>(Pg, Wf);
  gemm16_abt<<<dim3(256 / 128, MR_ / 128), 256, 0, stream>>>(x, Wf, kvqz, MR_, 256, DIM_);
  norm_k_kernel<<<MR_ / 4, 256, 0, stream>>>(kvqz);
  phase1_kernel<<<NCH * BB, 256, 0, stream>>>(kvqz, Tg, Mg, Bg);
  phase2_kernel<<<BB, 256, 0, stream>>>(Mg, Bg, Sall);
  phase3_kernel<<<NCH * BB, 256, 0, stream>>>(kvqz, Tg, Sall, ys);
  gemm16_abt<<<dim3(DIM_ / 128, MR_ / 128), 256, 0, stream>>>(ys, Wout, out, MR_, DIM_, NS_);
}

// Round 5
// 349.292 us; speedup vs baseline: 6.0854x; 1.1067x over previous
//
#include <hip/hip_runtime.h>
#include <math.h>

#define TT   2048
#define BB   8
#define DIM_ 1024
#define DI_  2048
#define NS_  64
#define MR_  (TT * BB)   // 16384 rows (t-major, b-minor)
#define NCH  32          // chunks of 64 steps
#define LD   68          // padded LDS leading dim (16B-aligned rows)
#define KSPL 16          // split-K factor for fuse GEMM
#define KCH  (DI_ / KSPL)

typedef _Float16 half8 __attribute__((ext_vector_type(8)));
typedef float floatx4 __attribute__((ext_vector_type(4)));

__device__ __forceinline__ float dot4(float4 a, float4 b) {
  return a.x * b.x + a.y * b.y + a.z * b.z + a.w * b.w;
}

// ---------------------------------------------------------------------------
// f16 MFMA GEMM: C[M,N] = A[M,K] * B[N,K]^T. A,B fp32 in memory, converted to
// f16 during LDS staging. 128x128 tile, BK=32, 4 waves x (4x4) 16x16x32 MFMA.
// ---------------------------------------------------------------------------
__global__ __launch_bounds__(256) void gemm16_abt(
    const float* __restrict__ A, const float* __restrict__ B,
    float* __restrict__ C, int M, int N, int K) {
  __shared__ _Float16 Ah[128 * 32];   // 8 KB, row-major [128][32]
  __shared__ _Float16 Bh[128 * 32];   // 8 KB
  const int tid  = threadIdx.x;
  const int m0   = blockIdx.y * 128;
  const int n0   = blockIdx.x * 128;
  const int wave = tid >> 6, lane = tid & 63;
  const int wm   = (wave >> 1) * 64;       // wave row base
  const int wn   = (wave & 1) * 64;        // wave col base
  const int quad = lane >> 4, l16 = lane & 15;
  const int srow = tid >> 2;               // 0..63
  const int skq  = (tid & 3) * 8;          // 0,8,16,24 (f16 elems)

  floatx4 acc[4][4];
#pragma unroll
  for (int i = 0; i < 4; ++i)
#pragma unroll
    for (int j = 0; j < 4; ++j) acc[i][j] = (floatx4)0.f;

  for (int k0 = 0; k0 < K; k0 += 32) {
    float4 a00 = *(const float4*)&A[(size_t)(m0 + srow)      * K + k0 + skq];
    float4 a01 = *(const float4*)&A[(size_t)(m0 + srow)      * K + k0 + skq + 4];
    float4 a10 = *(const float4*)&A[(size_t)(m0 + 64 + srow) * K + k0 + skq];
    float4 a11 = *(const float4*)&A[(size_t)(m0 + 64 + srow) * K + k0 + skq + 4];
    float4 b00 = *(const float4*)&B[(size_t)(n0 + srow)      * K + k0 + skq];
    float4 b01 = *(const float4*)&B[(size_t)(n0 + srow)      * K + k0 + skq + 4];
    float4 b10 = *(const float4*)&B[(size_t)(n0 + 64 + srow) * K + k0 + skq];
    float4 b11 = *(const float4*)&B[(size_t)(n0 + 64 + srow) * K + k0 + skq + 4];
    __syncthreads();
    {
      half8 ha0 = {(_Float16)a00.x, (_Float16)a00.y, (_Float16)a00.z, (_Float16)a00.w,
                   (_Float16)a01.x, (_Float16)a01.y, (_Float16)a01.z, (_Float16)a01.w};
      half8 ha1 = {(_Float16)a10.x, (_Float16)a10.y, (_Float16)a10.z, (_Float16)a10.w,
                   (_Float16)a11.x, (_Float16)a11.y, (_Float16)a11.z, (_Float16)a11.w};
      half8 hb0 = {(_Float16)b00.x, (_Float16)b00.y, (_Float16)b00.z, (_Float16)b00.w,
                   (_Float16)b01.x, (_Float16)b01.y, (_Float16)b01.z, (_Float16)b01.w};
      half8 hb1 = {(_Float16)b10.x, (_Float16)b10.y, (_Float16)b10.z, (_Float16)b10.w,
                   (_Float16)b11.x, (_Float16)b11.y, (_Float16)b11.z, (_Float16)b11.w};
      *(half8*)&Ah[(srow)      * 32 + skq] = ha0;
      *(half8*)&Ah[(64 + srow) * 32 + skq] = ha1;
      *(half8*)&Bh[(srow)      * 32 + skq] = hb0;
      *(half8*)&Bh[(64 + srow) * 32 + skq] = hb1;
    }
    __syncthreads();

    half8 af[4], bf[4];
#pragma unroll
    for (int mt = 0; mt < 4; ++mt)
      af[mt] = *(const half8*)&Ah[(wm + mt * 16 + l16) * 32 + quad * 8];
#pragma unroll
    for (int nt = 0; nt < 4; ++nt)
      bf[nt] = *(const half8*)&Bh[(wn + nt * 16 + l16) * 32 + quad * 8];
#pragma unroll
    for (int mt = 0; mt < 4; ++mt)
#pragma unroll
      for (int nt = 0; nt < 4; ++nt)
        acc[mt][nt] = __builtin_amdgcn_mfma_f32_16x16x32_f16(
            af[mt], bf[nt], acc[mt][nt], 0, 0, 0);
  }

#pragma unroll
  for (int mt = 0; mt < 4; ++mt) {
#pragma unroll
    for (int i = 0; i < 4; ++i) {
      const size_t r = (size_t)(m0 + wm + mt * 16 + quad * 4 + i) * N;
#pragma unroll
      for (int nt = 0; nt < 4; ++nt)
        C[r + n0 + wn + nt * 16 + l16] = acc[mt][nt][i];
    }
  }
}

// ---------------------------------------------------------------------------
// fuse GEMM (split-K): Pg[ks] partial of Wf[256][1024] = Wg[256][2048]*Win[2048][1024]
// ---------------------------------------------------------------------------
__global__ __launch_bounds__(256) void fuse_gemm_kernel(
    const float* __restrict__ Wk, const float* __restrict__ Wv,
    const float* __restrict__ Wq, const float* __restrict__ Wz,
    const float* __restrict__ Win, float* __restrict__ Pg) {
  __shared__ __align__(16) float As[16][132];
  __shared__ __align__(16) float Bs[16][132];
  const int tid = threadIdx.x;
  const int n0  = blockIdx.x * 128;
  const int m0  = blockIdx.y * 128;
  const int kb  = blockIdx.z * KCH;
  const int lrow = tid >> 2;
  const int lk4  = (tid & 3) << 2;
  const int tm   = (tid & 15) << 2;
  const int tn   = (tid >> 4) << 2;
  const float* Wg[4] = {Wk, Wv, Wq, Wz};
  const int ra = m0 + lrow, rb = m0 + 64 + lrow;
  const float* arow0 = Wg[ra >> 6] + (size_t)(ra & 63) * DI_;
  const float* arow1 = Wg[rb >> 6] + (size_t)(rb & 63) * DI_;
  const int brow = tid >> 5;
  const int bcol = (tid & 31) << 2;

  float acc[8][8];
#pragma unroll
  for (int i = 0; i < 8; ++i)
#pragma unroll
    for (int j = 0; j < 8; ++j) acc[i][j] = 0.f;

  for (int k0 = 0; k0 < KCH; k0 += 16) {
    float4 av0 = *(const float4*)&arow0[kb + k0 + lk4];
    float4 av1 = *(const float4*)&arow1[kb + k0 + lk4];
    float4 bv0 = *(const float4*)&Win[(size_t)(kb + k0 + brow)     * DIM_ + n0 + bcol];
    float4 bv1 = *(const float4*)&Win[(size_t)(kb + k0 + 8 + brow) * DIM_ + n0 + bcol];
    __syncthreads();
    As[lk4 + 0][lrow] = av0.x; As[lk4 + 1][lrow] = av0.y;
    As[lk4 + 2][lrow] = av0.z; As[lk4 + 3][lrow] = av0.w;
    As[lk4 + 0][64 + lrow] = av1.x; As[lk4 + 1][64 + lrow] = av1.y;
    As[lk4 + 2][64 + lrow] = av1.z; As[lk4 + 3][64 + lrow] = av1.w;
    *(float4*)&Bs[brow][bcol]     = bv0;
    *(float4*)&Bs[brow + 8][bcol] = bv1;
    __syncthreads();
#pragma unroll
    for (int kk = 0; kk < 16; ++kk) {
      float4 a0 = *(const float4*)&As[kk][tm];
      float4 a1 = *(const float4*)&As[kk][tm + 64];
      float4 b0 = *(const float4*)&Bs[kk][tn];
      float4 b1 = *(const float4*)&Bs[kk][tn + 64];
      float ar[8] = {a0.x, a0.y, a0.z, a0.w, a1.x, a1.y, a1.z, a1.w};
      float br[8] = {b0.x, b0.y, b0.z, b0.w, b1.x, b1.y, b1.z, b1.w};
#pragma unroll
      for (int i = 0; i < 8; ++i)
#pragma unroll
        for (int j = 0; j < 8; ++j)
          acc[i][j] = fmaf(ar[i], br[j], acc[i][j]);
    }
  }
  float* P = Pg + (size_t)blockIdx.z * (256 * DIM_);
#pragma unroll
  for (int i = 0; i < 8; ++i) {
    int r = m0 + tm + (i & 3) + ((i >> 2) << 6);
    float4 c0 = make_float4(acc[i][0], acc[i][1], acc[i][2], acc[i][3]);
    float4 c1 = make_float4(acc[i][4], acc[i][5], acc[i][6], acc[i][7]);
    *(float4*)&P[(size_t)r * DIM_ + n0 + tn]      = c0;
    *(float4*)&P[(size_t)r * DIM_ + n0 + tn + 64] = c1;
  }
}

// Wf[i] = sum_ks Pg[ks][i]
__global__ __launch_bounds__(256) void fuse_reduce_kernel(
    const float* __restrict__ Pg, float* __restrict__ Wf) {
  const size_t i = ((size_t)blockIdx.x * 256 + threadIdx.x) << 2;
  float4 s = *(const float4*)&Pg[i];
#pragma unroll
  for (int ks = 1; ks < KSPL; ++ks) {
    float4 p = *(const float4*)&Pg[(size_t)ks * (256 * DIM_) + i];
    s.x += p.x; s.y += p.y; s.z += p.z; s.w += p.w;
  }
  *(float4*)&Wf[i] = s;
}

// ---------------------------------------------------------------------------
// Unit-normalize each k row (first 64 cols of kvqz).
// ---------------------------------------------------------------------------
__global__ __launch_bounds__(256) void norm_k_kernel(float* __restrict__ kvqz) {
  const int wid  = (blockIdx.x * 256 + threadIdx.x) >> 6;
  const int lane = threadIdx.x & 63;
  float x = kvqz[(size_t)wid * 256 + lane];
  float s = x * x;
  s += __shfl_xor(s, 1);  s += __shfl_xor(s, 2);  s += __shfl_xor(s, 4);
  s += __shfl_xor(s, 8);  s += __shfl_xor(s, 16); s += __shfl_xor(s, 32);
  kvqz[(size_t)wid * 256 + lane] = x / (sqrtf(s) + 1e-6f);
}

// ---------------------------------------------------------------------------
// Phase 1: per chunk-batch:  A = K K^T ; Tt = inv(I+stril(A)) (transposed);
// P = T K ; Pv = T V ; M = I - P^T K ; B = Pv^T K.  Store Tt, M, B.
// ---------------------------------------------------------------------------
__global__ __launch_bounds__(256) void phase1_kernel(
    const float* __restrict__ kvqz, float* __restrict__ Tg,
    float* __restrict__ Mg, float* __restrict__ Bg) {
  __shared__ __align__(16) float Ks[64][LD];
  __shared__ __align__(16) float Vs[64][LD];
  __shared__ __align__(16) float As[64][LD];
  __shared__ __align__(16) float Tt[64][LD];
  __shared__ __align__(16) float Pv[64][LD];
  const int cb = blockIdx.x;
  const int c  = cb >> 3, b = cb & 7;
  const int t  = threadIdx.x;

  {
    const int tau = t >> 2, m0 = (t & 3) << 4;
    const float* src = kvqz + (size_t)((c * 64 + tau) * BB + b) * 256;
#pragma unroll
    for (int u = 0; u < 4; ++u) {
      *(float4*)&Ks[tau][m0 + 4 * u] = *(const float4*)&src[m0 + 4 * u];
      *(float4*)&Vs[tau][m0 + 4 * u] = *(const float4*)&src[64 + m0 + 4 * u];
    }
  }
  __syncthreads();

  const int i0 = (t >> 4) << 2;
  const int j0 = (t & 15) << 2;

  {  // A = K K^T
    float acc[4][4];
#pragma unroll
    for (int i = 0; i < 4; ++i)
#pragma unroll
      for (int j = 0; j < 4; ++j) acc[i][j] = 0.f;
    for (int m4 = 0; m4 < 64; m4 += 4) {
      float4 ar[4], br[4];
#pragma unroll
      for (int i = 0; i < 4; ++i) ar[i] = *(const float4*)&Ks[i0 + i][m4];
#pragma unroll
      for (int j = 0; j < 4; ++j) br[j] = *(const float4*)&Ks[j0 + j][m4];
#pragma unroll
      for (int i = 0; i < 4; ++i)
#pragma unroll
        for (int j = 0; j < 4; ++j) acc[i][j] += dot4(ar[i], br[j]);
    }
#pragma unroll
    for (int i = 0; i < 4; ++i)
      *(float4*)&As[i0 + i][j0] =
          make_float4(acc[i][0], acc[i][1], acc[i][2], acc[i][3]);
  }
  __syncthreads();

  if (t < 64) {  // column-parallel forward substitution (transposed storage)
    const int j = t;
    Tt[j][0] = (j == 0) ? 1.f : 0.f;
    for (int i = 1; i < 64; ++i) {
      float acc = 0.f;
      const int nf = i >> 2;
      for (int s4 = 0; s4 < nf; ++s4) {
        float4 av = *(const float4*)&As[i][4 * s4];
        float4 tv = *(const float4*)&Tt[j][4 * s4];
        acc += dot4(av, tv);
      }
      for (int s = 4 * nf; s < i; ++s) acc = fmaf(As[i][s], Tt[j][s], acc);
      Tt[j][i] = (i == j) ? 1.f : -acc;
    }
  }
  __syncthreads();

  {  // P = T K -> As ; Pv = T V
    float accP[4][4], accV[4][4];
#pragma unroll
    for (int i = 0; i < 4; ++i)
#pragma unroll
      for (int j = 0; j < 4; ++j) { accP[i][j] = 0.f; accV[i][j] = 0.f; }
    for (int s = 0; s < 64; ++s) {
      float4 tv = *(const float4*)&Tt[s][i0];
      float4 kv = *(const float4*)&Ks[s][j0];
      float4 vv = *(const float4*)&Vs[s][j0];
      float ta[4] = {tv.x, tv.y, tv.z, tv.w};
      float ka[4] = {kv.x, kv.y, kv.z, kv.w};
      float va[4] = {vv.x, vv.y, vv.z, vv.w};
#pragma unroll
      for (int i = 0; i < 4; ++i)
#pragma unroll
        for (int j = 0; j < 4; ++j) {
          accP[i][j] = fmaf(ta[i], ka[j], accP[i][j]);
          accV[i][j] = fmaf(ta[i], va[j], accV[i][j]);
        }
    }
    __syncthreads();
#pragma unroll
    for (int i = 0; i < 4; ++i) {
      *(float4*)&As[i0 + i][j0] =
          make_float4(accP[i][0], accP[i][1], accP[i][2], accP[i][3]);
      *(float4*)&Pv[i0 + i][j0] =
          make_float4(accV[i][0], accV[i][1], accV[i][2], accV[i][3]);
    }
  }
  __syncthreads();

  {  // M = I - P^T K ; B = Pv^T K  -> global
    float accM[4][4], accB[4][4];
#pragma unroll
    for (int i = 0; i < 4; ++i)
#pragma unroll
      for (int j = 0; j < 4; ++j) { accM[i][j] = 0.f; accB[i][j] = 0.f; }
    for (int s = 0; s < 64; ++s) {
      float4 pv  = *(const float4*)&As[s][i0];
      float4 pvv = *(const float4*)&Pv[s][i0];
      float4 kv  = *(const float4*)&Ks[s][j0];
      float pa[4] = {pv.x, pv.y, pv.z, pv.w};
      float qa[4] = {pvv.x, pvv.y, pvv.z, pvv.w};
      float ka[4] = {kv.x, kv.y, kv.z, kv.w};
#pragma unroll
      for (int i = 0; i < 4; ++i)
#pragma unroll
        for (int j = 0; j < 4; ++j) {
          accM[i][j] = fmaf(pa[i], ka[j], accM[i][j]);
          accB[i][j] = fmaf(qa[i], ka[j], accB[i][j]);
        }
    }
    const size_t base = (size_t)cb * 4096;
#pragma unroll
    for (int i = 0; i < 4; ++i) {
      float m0v = ((i0 + i) == (j0 + 0)) ? 1.f : 0.f;
      float m1v = ((i0 + i) == (j0 + 1)) ? 1.f : 0.f;
      float m2v = ((i0 + i) == (j0 + 2)) ? 1.f : 0.f;
      float m3v = ((i0 + i) == (j0 + 3)) ? 1.f : 0.f;
      *(float4*)&Mg[base + (size_t)(i0 + i) * 64 + j0] =
          make_float4(m0v - accM[i][0], m1v - accM[i][1],
                      m2v - accM[i][2], m3v - accM[i][3]);
      *(float4*)&Bg[base + (size_t)(i0 + i) * 64 + j0] =
          make_float4(accB[i][0], accB[i][1], accB[i][2], accB[i][3]);
    }
    const int fr = t >> 2, fc = (t & 3) << 4;
#pragma unroll
    for (int u = 0; u < 4; ++u)
      *(float4*)&Tg[base + (size_t)fr * 64 + fc + 4 * u] =
          *(const float4*)&Tt[fr][fc + 4 * u];
  }
}

// ---------------------------------------------------------------------------
// Phase 2 v2: rows of S are independent -> 128 single-wave blocks
// (8 batches x 16 row-groups of 4 rows). Zero barriers. S slice in registers
// (1 float4/lane); M_c staged in wave-private double-buffered LDS; M_{c+1}
// prefetched into VGPRs during compute. Same ascending-m summation as v1.
// ---------------------------------------------------------------------------
__global__ __launch_bounds__(64, 1) void phase2_kernel(
    const float* __restrict__ Mg, const float* __restrict__ Bg,
    float* __restrict__ Sall) {
  __shared__ __align__(16) float Mbuf[2][64 * 64];  // 2 x 16 KB
  __shared__ __align__(16) float Srow[2][4 * LD];   // padded, conflict-free
  const int bid  = blockIdx.x;
  const int b    = bid >> 4;           // batch
  const int w    = bid & 15;           // row group
  const int lane = threadIdx.x;        // 0..63
  const int rr   = lane >> 4;          // 0..3 (row within group)
  const int jc   = lane & 15;          // col group (4 cols)
  const int n    = w * 4 + rr;         // state row

  float4 pm[16];
  {  // preload M_0 and stage into buffer 0
    const float* mp = Mg + (size_t)b * 4096;
#pragma unroll
    for (int i = 0; i < 16; ++i)
      pm[i] = *(const float4*)&mp[i * 256 + lane * 4];
#pragma unroll
    for (int i = 0; i < 16; ++i)
      *(float4*)&Mbuf[0][i * 256 + lane * 4] = pm[i];
  }
  float4 cs = make_float4(0.f, 0.f, 0.f, 0.f);

  for (int c = 0; c < NCH; ++c) {
    const int cur = c & 1;
    const size_t cbase = (size_t)(c * BB + b) * 4096;
    // publish pre-chunk state + stage S row slice (wave-private LDS)
    *(float4*)&Sall[cbase + (size_t)n * 64 + jc * 4] = cs;
    *(float4*)&Srow[cur][rr * LD + jc * 4] = cs;
    // prefetch next chunk's M into VGPRs (latency hidden under compute)
    if (c + 1 < NCH) {
      const float* mp = Mg + (size_t)((c + 1) * BB + b) * 4096;
#pragma unroll
      for (int i = 0; i < 16; ++i)
        pm[i] = *(const float4*)&mp[i * 256 + lane * 4];
    }
    float4 bv = *(const float4*)&Bg[cbase + (size_t)n * 64 + jc * 4];

    float4 acc = make_float4(0.f, 0.f, 0.f, 0.f);
#pragma unroll
    for (int u = 0; u < 16; ++u) {
      float4 sv = *(const float4*)&Srow[cur][rr * LD + u * 4];
      float4 m0 = *(const float4*)&Mbuf[cur][(4 * u + 0) * 64 + jc * 4];
      float4 m1 = *(const float4*)&Mbuf[cur][(4 * u + 1) * 64 + jc * 4];
      float4 m2 = *(const float4*)&Mbuf[cur][(4 * u + 2) * 64 + jc * 4];
      float4 m3 = *(const float4*)&Mbuf[cur][(4 * u + 3) * 64 + jc * 4];
      acc.x = fmaf(sv.x, m0.x, acc.x); acc.y = fmaf(sv.x, m0.y, acc.y);
      acc.z = fmaf(sv.x, m0.z, acc.z); acc.w = fmaf(sv.x, m0.w, acc.w);
      acc.x = fmaf(sv.y, m1.x, acc.x); acc.y = fmaf(sv.y, m1.y, acc.y);
      acc.z = fmaf(sv.y, m1.z, acc.z); acc.w = fmaf(sv.y, m1.w, acc.w);
      acc.x = fmaf(sv.z, m2.x, acc.x); acc.y = fmaf(sv.z, m2.y, acc.y);
      acc.z = fmaf(sv.z, m2.z, acc.z); acc.w = fmaf(sv.z, m2.w, acc.w);
      acc.x = fmaf(sv.w, m3.x, acc.x); acc.y = fmaf(sv.w, m3.y, acc.y);
      acc.z = fmaf(sv.w, m3.z, acc.z); acc.w = fmaf(sv.w, m3.w, acc.w);
    }
    cs = make_float4(acc.x + bv.x, acc.y + bv.y, acc.z + bv.z, acc.w + bv.w);

    // stage next chunk's M into the other buffer (wave-private: no barrier)
    if (c + 1 < NCH) {
      const int nxt = cur ^ 1;
#pragma unroll
      for (int i = 0; i < 16; ++i)
        *(float4*)&Mbuf[nxt][i * 256 + lane * 4] = pm[i];
    }
  }
}

// ---------------------------------------------------------------------------
// Phase 3: Gt = (Q K^T)^T ; W = V - K S0^T ; U = T W ;
//   Y = Q S0^T + tril(G) U ; y = tanh(Y) * sigmoid(Z)  -> ys
// ---------------------------------------------------------------------------
__global__ __launch_bounds__(256) void phase3_kernel(
    const float* __restrict__ kvqz, const float* __restrict__ Tg,
    const float* __restrict__ Sall, float* __restrict__ ys) {
  __shared__ __align__(16) float Ks[64][LD];
  __shared__ __align__(16) float Qs[64][LD];
  __shared__ __align__(16) float S0s[64][LD];
  __shared__ __align__(16) float Tts[64][LD];
  __shared__ __align__(16) float Gts[64][LD];
  __shared__ __align__(16) float Ws[64][LD];
  __shared__ __align__(16) float Us[64][LD];
  const int cb = blockIdx.x;
  const int c  = cb >> 3, b = cb & 7;
  const int t  = threadIdx.x;
  const size_t base = (size_t)cb * 4096;

  {
    const int tau = t >> 2, m0 = (t & 3) << 4;
    const float* src = kvqz + (size_t)((c * 64 + tau) * BB + b) * 256;
#pragma unroll
    for (int u = 0; u < 4; ++u) {
      *(float4*)&Ks[tau][m0 + 4 * u]  = *(const float4*)&src[m0 + 4 * u];
      *(float4*)&Qs[tau][m0 + 4 * u]  = *(const float4*)&src[128 + m0 + 4 * u];
      *(float4*)&S0s[tau][m0 + 4 * u] = *(const float4*)&Sall[base + (size_t)tau * 64 + m0 + 4 * u];
      *(float4*)&Tts[tau][m0 + 4 * u] = *(const float4*)&Tg[base + (size_t)tau * 64 + m0 + 4 * u];
    }
  }
  __syncthreads();

  const int i0 = (t >> 4) << 2;
  const int j0 = (t & 15) << 2;

  {  // Gt[s][tq] = sum_m K[s][m] Q[tq][m]
    float acc[4][4];
#pragma unroll
    for (int i = 0; i < 4; ++i)
#pragma unroll
      for (int j = 0; j < 4; ++j) acc[i][j] = 0.f;
    for (int m4 = 0; m4 < 64; m4 += 4) {
      float4 kr[4], qr[4];
#pragma unroll
      for (int i = 0; i < 4; ++i) kr[i] = *(const float4*)&Ks[i0 + i][m4];
#pragma unroll
      for (int j = 0; j < 4; ++j) qr[j] = *(const float4*)&Qs[j0 + j][m4];
#pragma unroll
      for (int i = 0; i < 4; ++i)
#pragma unroll
        for (int j = 0; j < 4; ++j) acc[i][j] += dot4(kr[i], qr[j]);
    }
#pragma unroll
    for (int i = 0; i < 4; ++i)
      *(float4*)&Gts[i0 + i][j0] =
          make_float4(acc[i][0], acc[i][1], acc[i][2], acc[i][3]);
  }

  {  // W[tau][n] = V[tau][n] - sum_m K[tau][m] S0[n][m]
    float acc[4][4];
#pragma unroll
    for (int i = 0; i < 4; ++i) {
      const float* vrow = kvqz + (size_t)((c * 64 + i0 + i) * BB + b) * 256 + 64;
      float4 vv = *(const float4*)&vrow[j0];
      acc[i][0] = vv.x; acc[i][1] = vv.y; acc[i][2] = vv.z; acc[i][3] = vv.w;
    }
    for (int m4 = 0; m4 < 64; m4 += 4) {
      float4 kr[4], sr[4];
#pragma unroll
      for (int i = 0; i < 4; ++i) kr[i] = *(const float4*)&Ks[i0 + i][m4];
#pragma unroll
      for (int j = 0; j < 4; ++j) sr[j] = *(const float4*)&S0s[j0 + j][m4];
#pragma unroll
      for (int i = 0; i < 4; ++i)
#pragma unroll
        for (int j = 0; j < 4; ++j) acc[i][j] -= dot4(kr[i], sr[j]);
    }
    __syncthreads();
#pragma unroll
    for (int i = 0; i < 4; ++i)
      *(float4*)&Ws[i0 + i][j0] =
          make_float4(acc[i][0], acc[i][1], acc[i][2], acc[i][3]);
  }
  __syncthreads();

  float4 zv[4];
  {  // U[tq][n] = sum_s Tt[s][tq] W[s][n]
#pragma unroll
    for (int i = 0; i < 4; ++i) {
      const float* zrow = kvqz + (size_t)((c * 64 + i0 + i) * BB + b) * 256 + 192;
      zv[i] = *(const float4*)&zrow[j0];
    }
    float acc[4][4];
#pragma unroll
    for (int i = 0; i < 4; ++i)
#pragma unroll
      for (int j = 0; j < 4; ++j) acc[i][j] = 0.f;
    for (int s = 0; s < 64; ++s) {
      float4 tv = *(const float4*)&Tts[s][i0];
      float4 wv = *(const float4*)&Ws[s][j0];
      float ta[4] = {tv.x, tv.y, tv.z, tv.w};
      float wa[4] = {wv.x, wv.y, wv.z, wv.w};
#pragma unroll
      for (int i = 0; i < 4; ++i)
#pragma unroll
        for (int j = 0; j < 4; ++j) acc[i][j] = fmaf(ta[i], wa[j], acc[i][j]);
    }
    __syncthreads();
#pragma unroll
    for (int i = 0; i < 4; ++i)
      *(float4*)&Us[i0 + i][j0] =
          make_float4(acc[i][0], acc[i][1], acc[i][2], acc[i][3]);
  }
  __syncthreads();

  {  // Y = Q S0^T + tril(G) U ; out
    float acc[4][4];
#pragma unroll
    for (int i = 0; i < 4; ++i)
#pragma unroll
      for (int j = 0; j < 4; ++j) acc[i][j] = 0.f;
    for (int m4 = 0; m4 < 64; m4 += 4) {
      float4 qr[4], sr[4];
#pragma unroll
      for (int i = 0; i < 4; ++i) qr[i] = *(const float4*)&Qs[i0 + i][m4];
#pragma unroll
      for (int j = 0; j < 4; ++j) sr[j] = *(const float4*)&S0s[j0 + j][m4];
#pragma unroll
      for (int i = 0; i < 4; ++i)
#pragma unroll
        for (int j = 0; j < 4; ++j) acc[i][j] += dot4(qr[i], sr[j]);
    }
    for (int s = 0; s < 64; ++s) {
      float4 gv = *(const float4*)&Gts[s][i0];
      float4 uv = *(const float4*)&Us[s][j0];
      float ga[4] = {gv.x, gv.y, gv.z, gv.w};
      float ua[4] = {uv.x, uv.y, uv.z, uv.w};
#pragma unroll
      for (int i = 0; i < 4; ++i) {
        float gi = (s <= i0 + i) ? ga[i] : 0.f;
#pragma unroll
        for (int j = 0; j < 4; ++j) acc[i][j] = fmaf(gi, ua[j], acc[i][j]);
      }
    }
#pragma unroll
    for (int i = 0; i < 4; ++i) {
      float za[4] = {zv[i].x, zv[i].y, zv[i].z, zv[i].w};
      float4 o;
      float* op = &o.x;
#pragma unroll
      for (int j = 0; j < 4; ++j) {
        float e2 = __expf(2.f * acc[i][j]);
        float th = 1.f - 2.f / (e2 + 1.f);
        float sg = 1.f / (1.f + __expf(-za[j]));
        op[j] = th * sg;
      }
      *(float4*)&ys[(size_t)((c * 64 + i0 + i) * BB + b) * 64 + j0] = o;
    }
  }
}

// ---------------------------------------------------------------------------
extern "C" void kernel_launch(void* const* d_in, const int* in_sizes, int n_in,
                              void* d_out, int out_size, void* d_ws, size_t ws_size,
                              hipStream_t stream) {
  const float* x    = (const float*)d_in[0];
  const float* Win  = (const float*)d_in[1];
  const float* Wk   = (const float*)d_in[2];
  const float* Wv   = (const float*)d_in[3];
  const float* Wq   = (const float*)d_in[4];
  const float* Wz   = (const float*)d_in[5];
  const float* Wout = (const float*)d_in[6];
  float* out = (float*)d_out;

  char* ws = (char*)d_ws;
  float* Wf   = (float*)(ws);                  // 1 MB
  float* kvqz = (float*)(ws + (1u  << 20));    // 16 MB
  float* ys   = (float*)(ws + (17u << 20));    // 4 MB
  float* Tg   = (float*)(ws + (21u << 20));    // 4 MB
  float* Mg   = (float*)(ws + (25u << 20));    // 4 MB
  float* Bg   = (float*)(ws + (29u << 20));    // 4 MB
  float* Sall = (float*)(ws + (33u << 20));    // 4 MB  (37 MB total)
  // Pg (16 MB) aliases Tg..Sall: consumed by fuse_reduce before phase1 writes.
  float* Pg   = (float*)(ws + (21u << 20));

  fuse_gemm_kernel<<<dim3(DIM_ / 128, 2, KSPL), 256, 0, stream>>>(Wk, Wv, Wq, Wz, Win, Pg);
  fuse_reduce_kernel<<<(256 * DIM_ / 4) / 256, 256, 0, stream>>>(Pg, Wf);
  gemm16_abt<<<dim3(256 / 128, MR_ / 128), 256, 0, stream>>>(x, Wf, kvqz, MR_, 256, DIM_);
  norm_k_kernel<<<MR_ / 4, 256, 0, stream>>>(kvqz);
  phase1_kernel<<<NCH * BB, 256, 0, stream>>>(kvqz, Tg, Mg, Bg);
  phase2_kernel<<<16 * BB, 64, 0, stream>>>(Mg, Bg, Sall);
  phase3_kernel<<<NCH * BB, 256, 0, stream>>>(kvqz, Tg, Sall, ys);
  gemm16_abt<<<dim3(DIM_ / 128, MR_ / 128), 256, 0, stream>>>(ys, Wout, out, MR_, DIM_, NS_);
}